// Round 5
// baseline (354.618 us; speedup 1.0000x reference)
//
#include <hip/hip_runtime.h>

#define D_ 64
#define L_ 2
#define R_ 50
#define N_ 20001
#define A_ 6
#define E_ 30000
#define B_ 4
#define C_ 500
#define FEAT_ 128
#define SC_CAP 16384

__device__ __forceinline__ float rlane(float v, int k) {
  return __builtin_bit_cast(float, __builtin_amdgcn_readlane(__builtin_bit_cast(int, v), k));
}
__device__ __forceinline__ float wave_sum(float v) {
#pragma unroll
  for (int off = 32; off; off >>= 1) v += __shfl_xor(v, off);
  return v;
}

// ---------- init: pos_search + seed scatter into delta, mark dirty ----------

__global__ void init_kernel(const int* __restrict__ r_idx, const int* __restrict__ ents,
                            const int* __restrict__ arity,
                            const float* __restrict__ pos_table,
                            const float* __restrict__ query_emb,
                            float* __restrict__ delta, int* __restrict__ dirty,
                            int* __restrict__ meta) {
  int b = blockIdx.x, t = threadIdx.x;
  __shared__ int diff[A_];
  if (t < A_) diff[t] = 0;
  __syncthreads();
#pragma unroll
  for (int a = 0; a < A_; ++a) {
    int v0 = ents[(b * C_) * A_ + a];
    int dd = 0;
    for (int c = t; c < C_; c += 256) dd |= (ents[(b * C_ + c) * A_ + a] != v0);
    if (dd) diff[a] = 1;
  }
  __syncthreads();
  int ps = 0;
  for (int a = A_ - 1; a >= 0; --a) if (diff[a]) ps = a;
  int qr = r_idx[b * C_];
  if (t == 0) { meta[b] = ps; meta[B_ + b] = qr; }
  int ar = arity[b * C_];
  int lane = t & 63;
  for (int a = (t >> 6); a < A_; a += 4) {
    if (a < ar && a != ps) {
      int n = ents[(b * C_) * A_ + a];
      float val = query_emb[qr * D_ + lane] + pos_table[(a + 1) * D_ + lane];
      atomicAdd(&delta[(n * B_ + b) * D_ + lane], val);
      if (lane == 0) atomicOr(&dirty[n], 1 << b);
    }
  }
}

// ---------- CSR build ----------

__global__ void count_kernel(const int* __restrict__ edge_list, int* __restrict__ cnt) {
  int i = blockIdx.x * blockDim.x + threadIdx.x;
  if (i >= E_ * A_) return;
  int n = edge_list[i];
  if (n) atomicAdd(&cnt[n], 1);
}

#define SCAN_T 1024
#define CHUNK 20
__global__ void scan_kernel(int* __restrict__ cnt, int* __restrict__ off) {
  __shared__ int part[SCAN_T];
  int t = threadIdx.x;
  int base = t * CHUNK;
  int v[CHUNK];
  int s = 0;
#pragma unroll
  for (int i = 0; i < CHUNK; ++i) {
    int idx = base + i;
    v[i] = (idx < N_) ? cnt[idx] : 0;
    s += v[i];
  }
  part[t] = s;
  __syncthreads();
  for (int d = 1; d < SCAN_T; d <<= 1) {
    int x = part[t];
    int y = (t >= d) ? part[t - d] : 0;
    __syncthreads();
    part[t] = x + y;
    __syncthreads();
  }
  int run = (t == 0) ? 0 : part[t - 1];
#pragma unroll
  for (int i = 0; i < CHUNK; ++i) {
    int idx = base + i;
    if (idx < N_) {
      off[idx] = run;
      cnt[idx] = run;  // cursor for fill
      run += v[i];
    }
  }
  if (t == SCAN_T - 1) off[N_] = part[SCAN_T - 1];
}

__global__ void fill_kernel(const int* __restrict__ edge_list, int* __restrict__ cur,
                            int* __restrict__ pairs) {
  int i = blockIdx.x * blockDim.x + threadIdx.x;
  if (i >= E_ * A_) return;
  int n = edge_list[i];
  if (n) {
    int p = atomicAdd(&cur[n], 1);
    pairs[p] = i;
  }
}

// ---------- batch-independent per-edge sums: SB_e = rel ⊙ (P_e + Σ H[members]) ----------

__global__ __launch_bounds__(512) void sb_kernel(const int* __restrict__ edge_list,
                                                 const int* __restrict__ rel_list,
                                                 const float* __restrict__ pos_table,
                                                 const float* __restrict__ rel_emb_l,
                                                 const float* __restrict__ Hl,
                                                 float* __restrict__ SB) {
  int e = (blockIdx.x * 512 + threadIdx.x) >> 6;
  int lane = threadIdx.x & 63;
  if (e >= E_) return;
  int mem[A_];
#pragma unroll
  for (int a = 0; a < A_; ++a) mem[a] = edge_list[e * A_ + a];
  float s = 0.f;
  if (Hl) {
#pragma unroll
    for (int a = 0; a < A_; ++a)
      if (mem[a]) s += Hl[mem[a] * D_ + lane];
  }
#pragma unroll
  for (int a = 0; a < A_; ++a)
    if (mem[a]) s += pos_table[(a + 1) * D_ + lane];
  float rel = rel_emb_l[rel_list[e] * D_ + lane];
  SB[e * D_ + lane] = s * rel;
}

// ---------- batch-independent node update: agg gather + dual GEMM + LN + relu + residual ----------

__global__ __launch_bounds__(256) void main_kernel(
    const int* __restrict__ csr_off, const int* __restrict__ pairs,
    const int* __restrict__ rel_list, const float* __restrict__ pos_table,
    const float* __restrict__ rel_emb_l, const float* __restrict__ SB,
    const float* __restrict__ Hl, float* __restrict__ Hn,
    const float* __restrict__ Wa, const float* __restrict__ Ws,
    const float* __restrict__ bl_, const float* __restrict__ g_,
    const float* __restrict__ be_) {
  __shared__ float A_lds[32 * 68];
  __shared__ float B_lds[64 * 64];
  int t = threadIdx.x;
  int m0 = blockIdx.x * 32;
  int ty = t >> 4, tx = t & 15;
  int wv = t >> 6, l = t & 63;

  // stage B = W_agg
#pragma unroll
  for (int it = 0; it < 4; ++it) {
    int idx = t + 256 * it;
    int k = idx >> 4, c4 = (idx & 15) * 4;
    *reinterpret_cast<float4*>(&B_lds[k * 64 + c4]) =
        *reinterpret_cast<const float4*>(&Wa[k * 64 + c4]);
  }

  // phase A: AGG for 32 nodes (8 per wave), 8-deep chunked gathers
  for (int q = 0; q < 8; ++q) {
    int li = wv * 8 + q;
    int n = m0 + li;
    float aggv = 0.f;
    if (n < N_) {
      float hv = Hl[n * D_ + l];
      float ss = 0.f, rs = 0.f, ps = 0.f;
      int p0 = __builtin_amdgcn_readfirstlane(csr_off[n]);
      int p1 = __builtin_amdgcn_readfirstlane(csr_off[n + 1]);
      for (int p = p0; p < p1; p += 8) {
        int cnt = p1 - p;
        int idx8[8];
#pragma unroll
        for (int u = 0; u < 8; ++u) idx8[u] = (u < cnt) ? pairs[p + u] : -1;
#pragma unroll
        for (int u = 0; u < 8; ++u) {
          if (idx8[u] >= 0) {
            int e = idx8[u] / 6, a = idx8[u] - e * 6;
            float sv = SB[e * D_ + l];
            float rv = rel_emb_l[rel_list[e] * D_ + l];
            float pv = pos_table[(a + 1) * D_ + l];
            ss += sv; rs += rv; ps = fmaf(rv, pv, ps);
          }
        }
      }
      aggv = ss - hv * rs - ps;
    }
    A_lds[li * 68 + l] = aggv;
  }
  __syncthreads();

  // GEMM half 0: acc = AGG @ Wa + b_lin
  float acc[2][4];
  float4 bl4 = *reinterpret_cast<const float4*>(&bl_[tx * 4]);
#pragma unroll
  for (int i = 0; i < 2; ++i) {
    acc[i][0] = bl4.x; acc[i][1] = bl4.y; acc[i][2] = bl4.z; acc[i][3] = bl4.w;
  }
#pragma unroll 8
  for (int k = 0; k < 64; ++k) {
    float4 b4 = *reinterpret_cast<const float4*>(&B_lds[k * 64 + tx * 4]);
    float a0 = A_lds[(ty * 2 + 0) * 68 + k];
    float a1 = A_lds[(ty * 2 + 1) * 68 + k];
    acc[0][0] = fmaf(a0, b4.x, acc[0][0]); acc[0][1] = fmaf(a0, b4.y, acc[0][1]);
    acc[0][2] = fmaf(a0, b4.z, acc[0][2]); acc[0][3] = fmaf(a0, b4.w, acc[0][3]);
    acc[1][0] = fmaf(a1, b4.x, acc[1][0]); acc[1][1] = fmaf(a1, b4.y, acc[1][1]);
    acc[1][2] = fmaf(a1, b4.z, acc[1][2]); acc[1][3] = fmaf(a1, b4.w, acc[1][3]);
  }
  __syncthreads();

  // restage A = Hl tile, B = W_self
#pragma unroll
  for (int it = 0; it < 2; ++it) {
    int idx4 = t + 256 * it;  // 0..511
    int r = idx4 >> 4, kq = (idx4 & 15) * 4;
    int row = m0 + r;
    float4 v = make_float4(0.f, 0.f, 0.f, 0.f);
    if (row < N_) v = *reinterpret_cast<const float4*>(&Hl[row * D_ + kq]);
    *reinterpret_cast<float4*>(&A_lds[r * 68 + kq]) = v;
  }
#pragma unroll
  for (int it = 0; it < 4; ++it) {
    int idx = t + 256 * it;
    int k = idx >> 4, c4 = (idx & 15) * 4;
    *reinterpret_cast<float4*>(&B_lds[k * 64 + c4]) =
        *reinterpret_cast<const float4*>(&Ws[k * 64 + c4]);
  }
  __syncthreads();

  // GEMM half 1: acc += H @ Ws
#pragma unroll 8
  for (int k = 0; k < 64; ++k) {
    float4 b4 = *reinterpret_cast<const float4*>(&B_lds[k * 64 + tx * 4]);
    float a0 = A_lds[(ty * 2 + 0) * 68 + k];
    float a1 = A_lds[(ty * 2 + 1) * 68 + k];
    acc[0][0] = fmaf(a0, b4.x, acc[0][0]); acc[0][1] = fmaf(a0, b4.y, acc[0][1]);
    acc[0][2] = fmaf(a0, b4.z, acc[0][2]); acc[0][3] = fmaf(a0, b4.w, acc[0][3]);
    acc[1][0] = fmaf(a1, b4.x, acc[1][0]); acc[1][1] = fmaf(a1, b4.y, acc[1][1]);
    acc[1][2] = fmaf(a1, b4.z, acc[1][2]); acc[1][3] = fmaf(a1, b4.w, acc[1][3]);
  }
  __syncthreads();

  // out tile -> LDS
#pragma unroll
  for (int i = 0; i < 2; ++i) {
    float4 v = make_float4(acc[i][0], acc[i][1], acc[i][2], acc[i][3]);
    *reinterpret_cast<float4*>(&A_lds[(ty * 2 + i) * 68 + tx * 4]) = v;
  }
  __syncthreads();

  // LN + relu + residual -> Hn
  float g = g_[l], be = be_[l];
#pragma unroll 4
  for (int rr = 0; rr < 8; ++rr) {
    int r = wv * 8 + rr;
    int row = m0 + r;
    float x = A_lds[r * 68 + l];
    float mu = wave_sum(x) * (1.f / 64.f);
    float dx = x - mu;
    float var = wave_sum(dx * dx) * (1.f / 64.f);
    float y = dx * rsqrtf(var + 1e-5f) * g + be;
    if (row < N_) Hn[row * D_ + l] = fmaxf(y, 0.f) + Hl[row * D_ + l];
  }
}

// ---------- dirty propagation ----------

__global__ void copy_dirty_kernel(const int* __restrict__ src, int* __restrict__ dst) {
  int n = blockIdx.x * blockDim.x + threadIdx.x;
  if (n < N_) dst[n] = src[n];
}

__global__ void edge_prop_kernel(const int* __restrict__ edge_list,
                                 const int* __restrict__ dirty_l, int* __restrict__ dirty_n,
                                 int* __restrict__ elist, int* __restrict__ ctrs) {
  int e = blockIdx.x * blockDim.x + threadIdx.x;
  if (e >= E_) return;
  int mem[A_];
  int m = 0;
#pragma unroll
  for (int a = 0; a < A_; ++a) {
    mem[a] = edge_list[e * A_ + a];
    if (mem[a]) m |= dirty_l[mem[a]];
  }
  if (m) {
#pragma unroll
    for (int a = 0; a < A_; ++a)
      if (mem[a]) atomicOr(&dirty_n[mem[a]], m);
    int s = atomicAdd(&ctrs[0], 1);
    elist[s] = e | (m << 16);
  }
}

// ---------- per-dirty-edge correction rows: Scorr = rel ⊙ Σ delta[members] ----------

__global__ __launch_bounds__(256) void scorr_kernel(
    const int* __restrict__ elist, const int* __restrict__ edge_list,
    const int* __restrict__ rel_list, const float* __restrict__ rel_emb_l,
    const float* __restrict__ delta, float* __restrict__ Scorr,
    int* __restrict__ emap, int* __restrict__ ctrs) {
  int cnt = ctrs[0];
  int w = blockIdx.x * 4 + (threadIdx.x >> 6);
  int nw = gridDim.x * 4;
  int lane = threadIdx.x & 63;
  for (int i = w; i < cnt; i += nw) {
    int pk = elist[i];
    int e = pk & 0xFFFF, m = pk >> 16;
    float rel = rel_emb_l[rel_list[e] * D_ + lane];
    int mem[A_];
#pragma unroll
    for (int a = 0; a < A_; ++a) mem[a] = edge_list[e * A_ + a];
#pragma unroll
    for (int b = 0; b < B_; ++b) {
      if ((m >> b) & 1) {
        float s = 0.f;
#pragma unroll
        for (int a = 0; a < A_; ++a)
          if (mem[a]) s += delta[(mem[a] * B_ + b) * D_ + lane];
        int slot = 0;
        if (lane == 0) slot = atomicAdd(&ctrs[1], 1);
        slot = __shfl(slot, 0);
        if (slot < SC_CAP) {
          Scorr[slot * D_ + lane] = rel * s;
          if (lane == 0) emap[e * B_ + b] = slot + 1;
        }
      }
    }
  }
}

__global__ void compact_kernel(const int* __restrict__ dirty_n, int* __restrict__ nlist,
                               int* __restrict__ ctrs) {
  int n = blockIdx.x * blockDim.x + threadIdx.x;
  if (n >= N_) return;
  int m = dirty_n[n];
  if (m) {
    int s = atomicAdd(&ctrs[2], 1);
    nlist[s] = n | (m << 16);
  }
}

// ---------- exact recompute of dirty rows; delta_{l+1} = h_new - H_{l+1} ----------

__global__ __launch_bounds__(256) void corr_kernel(
    const int* __restrict__ nlist, const int* __restrict__ ctrs,
    const int* __restrict__ csr_off, const int* __restrict__ pairs,
    const int* __restrict__ rel_list, const float* __restrict__ pos_table,
    const float* __restrict__ rel_emb_l, const float* __restrict__ SB,
    const float* __restrict__ Scorr, const int* __restrict__ emap,
    const float* __restrict__ Hl, const float* __restrict__ Hn,
    float* __restrict__ delta,
    const float* __restrict__ Wa, const float* __restrict__ Ws,
    const float* __restrict__ bl_, const float* __restrict__ g_,
    const float* __restrict__ be_) {
  __shared__ float WaL[64 * 64];
  __shared__ float WsL[64 * 64];
  int t = threadIdx.x;
#pragma unroll
  for (int it = 0; it < 16; ++it) {
    int idx = t + 256 * it;
    WaL[idx] = Wa[idx];
    WsL[idx] = Ws[idx];
  }
  __syncthreads();
  int cntn = ctrs[2];
  int w = blockIdx.x * 4 + (t >> 6);
  int nw = gridDim.x * 4;
  int lane = t & 63;
  float blv = bl_[lane], gv = g_[lane], bev = be_[lane];
  for (int i = w; i < cntn; i += nw) {
    int pk = nlist[i];
    int n = pk & 0xFFFF, m = pk >> 16;
    int p0 = csr_off[n], p1 = csr_off[n + 1];
    float Hlv = Hl[n * D_ + lane];
    float Hnv = Hn[n * D_ + lane];
#pragma unroll
    for (int b = 0; b < B_; ++b) {
      if ((m >> b) & 1) {
        float hv = Hlv + delta[(n * B_ + b) * D_ + lane];
        float ss = 0.f, rs = 0.f, ps = 0.f;
        for (int p = p0; p < p1; ++p) {
          int ii = pairs[p];
          int e = ii / 6, a = ii - e * 6;
          float sv = SB[e * D_ + lane];
          int ei = emap[e * B_ + b];
          if (ei) sv += Scorr[(ei - 1) * D_ + lane];
          float rv = rel_emb_l[rel_list[e] * D_ + lane];
          float pv = pos_table[(a + 1) * D_ + lane];
          ss += sv; rs += rv; ps = fmaf(rv, pv, ps);
        }
        float aggv = ss - hv * rs - ps;
        float out = blv;
#pragma unroll 16
        for (int k = 0; k < 64; ++k) {
          out = fmaf(rlane(aggv, k), WaL[k * 64 + lane], out);
          out = fmaf(rlane(hv, k), WsL[k * 64 + lane], out);
        }
        float mu = wave_sum(out) * (1.f / 64.f);
        float dx = out - mu;
        float var = wave_sum(dx * dx) * (1.f / 64.f);
        float y = dx * rsqrtf(var + 1e-5f) * gv + bev;
        float hnew = fmaxf(y, 0.f) + hv;
        delta[(n * B_ + b) * D_ + lane] = hnew - Hnv;
      }
    }
  }
}

// ---------- scoring MLP: h2[cand][b] = H2[cand] + delta[cand][b] ----------

__global__ __launch_bounds__(256) void score_kernel(
    const int* __restrict__ ents, const float* __restrict__ H2,
    const float* __restrict__ delta, const int* __restrict__ meta,
    const float* __restrict__ query_emb,
    const float* __restrict__ W1, const float* __restrict__ b1,
    const float* __restrict__ W2, const float* __restrict__ b2,
    float* __restrict__ out) {
  int w = (blockIdx.x * blockDim.x + threadIdx.x) >> 6;
  int lane = threadIdx.x & 63;
  if (w >= B_ * C_) return;
  int b = w / C_;
  int c = w - b * C_;
  int ps = meta[b];
  int qr = meta[B_ + b];
  int cand = ents[(b * C_ + c) * A_ + ps];
  float fv = H2[cand * D_ + lane] + delta[(cand * B_ + b) * D_ + lane];
  float qv = query_emb[qr * D_ + lane];
  float hid0 = b1[lane];
  float hid1 = b1[D_ + lane];
#pragma unroll
  for (int k = 0; k < D_; ++k) {
    float f = rlane(fv, k);
    hid0 = fmaf(f, W1[k * FEAT_ + lane], hid0);
    hid1 = fmaf(f, W1[k * FEAT_ + D_ + lane], hid1);
  }
#pragma unroll
  for (int k = 0; k < D_; ++k) {
    float q = rlane(qv, k);
    hid0 = fmaf(q, W1[(D_ + k) * FEAT_ + lane], hid0);
    hid1 = fmaf(q, W1[(D_ + k) * FEAT_ + D_ + lane], hid1);
  }
  float accs = fmaxf(hid0, 0.f) * W2[lane] + fmaxf(hid1, 0.f) * W2[D_ + lane];
  accs = wave_sum(accs);
  if (lane == 0) out[w] = accs + b2[0];
}

// ---------- launch ----------

extern "C" void kernel_launch(void* const* d_in, const int* in_sizes, int n_in,
                              void* d_out, int out_size, void* d_ws, size_t ws_size,
                              hipStream_t stream) {
  const int* r_idx = (const int*)d_in[0];
  const int* ents = (const int*)d_in[1];
  const int* arity = (const int*)d_in[2];
  const int* edge_list = (const int*)d_in[3];
  const int* rel_list = (const int*)d_in[4];
  const float* pos_table = (const float*)d_in[5];
  const float* query_emb = (const float*)d_in[6];
  const float* rel_emb = (const float*)d_in[7];
  const float* W_agg = (const float*)d_in[8];
  const float* W_self = (const float*)d_in[9];
  const float* b_lin = (const float*)d_in[10];
  const float* ln_g = (const float*)d_in[11];
  const float* ln_b = (const float*)d_in[12];
  const float* W1 = (const float*)d_in[13];
  const float* b1 = (const float*)d_in[14];
  const float* W2 = (const float*)d_in[15];
  const float* b2 = (const float*)d_in[16];
  float* out = (float*)d_out;

  char* ws = (char*)d_ws;
  // layout (bytes)
  float* H0    = (float*)(ws + 0);          //  5,120,256
  float* H1    = (float*)(ws + 5120256);    //  5,120,256
  float* delta = (float*)(ws + 10240512);   // 20,481,024
  float* SB    = (float*)(ws + 30721536);   //  7,680,000
  float* Scorr = (float*)(ws + 38401536);   //  4,194,304
  int* emap    = (int*)(ws + 42595840);     //    480,000
  int* cnt     = (int*)(ws + 43075840);     //     80,008
  int* csr_off = (int*)(ws + 43155856);     //     80,008
  int* pairs   = (int*)(ws + 43235872);     //    720,000
  int* dirtyA  = (int*)(ws + 43955872);     //     80,004
  int* dirtyB  = (int*)(ws + 44035888);     //     80,004
  int* elist   = (int*)(ws + 44115904);     //    120,000
  int* nlist   = (int*)(ws + 44235904);     //     80,004
  int* ctrs    = (int*)(ws + 44315920);     //         64
  int* meta    = (int*)(ws + 44315984);     //         32
  if (ws_size < 44316016) return;  // insufficient scratch; output stays poisoned

  hipMemsetAsync(H0, 0, 5120256, stream);
  hipMemsetAsync(delta, 0, 20481024, stream);
  hipMemsetAsync(cnt, 0, (N_ + 1) * sizeof(int), stream);
  hipMemsetAsync(dirtyA, 0, N_ * sizeof(int), stream);

  init_kernel<<<B_, 256, 0, stream>>>(r_idx, ents, arity, pos_table, query_emb,
                                      delta, dirtyA, meta);
  count_kernel<<<(E_ * A_ + 255) / 256, 256, 0, stream>>>(edge_list, cnt);
  scan_kernel<<<1, SCAN_T, 0, stream>>>(cnt, csr_off);
  fill_kernel<<<(E_ * A_ + 255) / 256, 256, 0, stream>>>(edge_list, cnt, pairs);

  for (int l = 0; l < L_; ++l) {
    const float* rel_l = rel_emb + l * R_ * D_;
    const float* Wa = W_agg + l * D_ * D_;
    const float* Wsf = W_self + l * D_ * D_;
    const float* bl = b_lin + l * D_;
    const float* lg = ln_g + l * D_;
    const float* lb = ln_b + l * D_;
    float* Hl = (l == 0) ? H0 : H1;
    float* Hn = (l == 0) ? H1 : H0;
    int* d_l = (l == 0) ? dirtyA : dirtyB;
    int* d_n = (l == 0) ? dirtyB : dirtyA;

    hipMemsetAsync(ctrs, 0, 64, stream);
    hipMemsetAsync(emap, 0, E_ * B_ * sizeof(int), stream);

    sb_kernel<<<E_ / 8, 512, 0, stream>>>(edge_list, rel_list, pos_table, rel_l,
                                          (l == 0) ? nullptr : Hl, SB);
    main_kernel<<<(N_ + 31) / 32, 256, 0, stream>>>(
        csr_off, pairs, rel_list, pos_table, rel_l, SB, Hl, Hn,
        Wa, Wsf, bl, lg, lb);
    copy_dirty_kernel<<<(N_ + 255) / 256, 256, 0, stream>>>(d_l, d_n);
    edge_prop_kernel<<<(E_ + 255) / 256, 256, 0, stream>>>(edge_list, d_l, d_n,
                                                           elist, ctrs);
    scorr_kernel<<<128, 256, 0, stream>>>(elist, edge_list, rel_list, rel_l,
                                          delta, Scorr, emap, ctrs);
    compact_kernel<<<(N_ + 255) / 256, 256, 0, stream>>>(d_n, nlist, ctrs);
    corr_kernel<<<128, 256, 0, stream>>>(nlist, ctrs, csr_off, pairs, rel_list,
                                         pos_table, rel_l, SB, Scorr, emap,
                                         Hl, Hn, delta, Wa, Wsf, bl, lg, lb);
  }

  score_kernel<<<(B_ * C_ + 3) / 4, 256, 0, stream>>>(ents, H0, delta, meta,
                                                      query_emb, W1, b1, W2, b2, out);
  (void)in_sizes; (void)n_in; (void)out_size;
}

// Round 6
// 172.227 us; speedup vs baseline: 2.0590x; 2.0590x over previous
//
#include <hip/hip_runtime.h>

#define D_ 64
#define L_ 2
#define R_ 50
#define N_ 20001
#define A_ 6
#define E_ 30000
#define B_ 4
#define C_ 500
#define FEAT_ 128
#define SC_CAP 8192

__device__ __forceinline__ float rlane(float v, int k) {
  return __builtin_bit_cast(float, __builtin_amdgcn_readlane(__builtin_bit_cast(int, v), k));
}
__device__ __forceinline__ float wave_sum(float v) {
#pragma unroll
  for (int off = 32; off; off >>= 1) v += __shfl_xor(v, off);
  return v;
}

// ---------- init: pos_search + seed table + dirty marks ----------
// seeds: slot = b*A_+a; seednode[slot] (0 = invalid), seedvec[slot][64]
// h0[n,b] = sum over slots of batch b with seednode==n of seedvec.

__global__ void init_kernel(const int* __restrict__ r_idx, const int* __restrict__ ents,
                            const int* __restrict__ arity,
                            const float* __restrict__ pos_table,
                            const float* __restrict__ query_emb,
                            int* __restrict__ seednode, float* __restrict__ seedvec,
                            int* __restrict__ dirty, int* __restrict__ meta) {
  int b = blockIdx.x, t = threadIdx.x;
  __shared__ int diff[A_];
  if (t < A_) diff[t] = 0;
  __syncthreads();
#pragma unroll
  for (int a = 0; a < A_; ++a) {
    int v0 = ents[(b * C_) * A_ + a];
    int dd = 0;
    for (int c = t; c < C_; c += 256) dd |= (ents[(b * C_ + c) * A_ + a] != v0);
    if (dd) diff[a] = 1;
  }
  __syncthreads();
  int ps = 0;
  for (int a = A_ - 1; a >= 0; --a) if (diff[a]) ps = a;
  int qr = r_idx[b * C_];
  if (t == 0) { meta[b] = ps; meta[B_ + b] = qr; }
  int ar = arity[b * C_];
  int lane = t & 63;
  for (int a = (t >> 6); a < A_; a += 4) {
    int slot = b * A_ + a;
    if (a < ar && a != ps) {
      int n = ents[(b * C_) * A_ + a];
      seedvec[slot * D_ + lane] = query_emb[qr * D_ + lane] + pos_table[(a + 1) * D_ + lane];
      if (lane == 0) {
        seednode[slot] = n;
        atomicOr(&dirty[n], 1 << b);
      }
    } else {
      if (lane == 0) seednode[slot] = 0;
    }
  }
}

// ---------- CSR build ----------

__global__ void count_kernel(const int* __restrict__ edge_list, int* __restrict__ cnt) {
  int i = blockIdx.x * blockDim.x + threadIdx.x;
  if (i >= E_ * A_) return;
  int n = edge_list[i];
  if (n) atomicAdd(&cnt[n], 1);
}

#define SCAN_T 1024
#define CHUNK 20
__global__ void scan_kernel(int* __restrict__ cnt, int* __restrict__ off) {
  __shared__ int part[SCAN_T];
  int t = threadIdx.x;
  int base = t * CHUNK;
  int v[CHUNK];
  int s = 0;
#pragma unroll
  for (int i = 0; i < CHUNK; ++i) {
    int idx = base + i;
    v[i] = (idx < N_) ? cnt[idx] : 0;
    s += v[i];
  }
  part[t] = s;
  __syncthreads();
  for (int d = 1; d < SCAN_T; d <<= 1) {
    int x = part[t];
    int y = (t >= d) ? part[t - d] : 0;
    __syncthreads();
    part[t] = x + y;
    __syncthreads();
  }
  int run = (t == 0) ? 0 : part[t - 1];
#pragma unroll
  for (int i = 0; i < CHUNK; ++i) {
    int idx = base + i;
    if (idx < N_) {
      off[idx] = run;
      cnt[idx] = run;  // cursor for fill
      run += v[i];
    }
  }
  if (t == SCAN_T - 1) off[N_] = part[SCAN_T - 1];
}

__global__ void fill_kernel(const int* __restrict__ edge_list, int* __restrict__ cur,
                            int* __restrict__ pairs) {
  int i = blockIdx.x * blockDim.x + threadIdx.x;
  if (i >= E_ * A_) return;
  int n = edge_list[i];
  if (n) {
    int p = atomicAdd(&cur[n], 1);
    pairs[p] = i;
  }
}

// ---------- layer-0 per-edge sums (H0=0): SB_e = rel ⊙ Σ_members pos ----------

__global__ __launch_bounds__(512) void sb0_kernel(const int* __restrict__ edge_list,
                                                  const int* __restrict__ rel_list,
                                                  const float* __restrict__ pos_table,
                                                  const float* __restrict__ rel_emb_l,
                                                  float* __restrict__ SB) {
  int e = (blockIdx.x * 512 + threadIdx.x) >> 6;
  int lane = threadIdx.x & 63;
  if (e >= E_) return;
  float s = 0.f;
#pragma unroll
  for (int a = 0; a < A_; ++a)
    if (edge_list[e * A_ + a]) s += pos_table[(a + 1) * D_ + lane];
  float rel = rel_emb_l[rel_list[e] * D_ + lane];
  SB[e * D_ + lane] = s * rel;
}

// ---------- layer-0 batch-collapsed node update (h0=0): agg@Wa + b_lin, LN, relu -> h1 ----------

__global__ __launch_bounds__(256) void mainL0_kernel(
    const int* __restrict__ csr_off, const int* __restrict__ pairs,
    const int* __restrict__ rel_list, const float* __restrict__ pos_table,
    const float* __restrict__ rel_emb_l, const float* __restrict__ SB,
    float* __restrict__ h1,
    const float* __restrict__ Wa, const float* __restrict__ bl_,
    const float* __restrict__ g_, const float* __restrict__ be_) {
  __shared__ float A_lds[32 * 68];
  __shared__ float B_lds[64 * 64];
  int t = threadIdx.x;
  int m0 = blockIdx.x * 32;
  int ty = t >> 4, tx = t & 15;
  int wv = t >> 6, l = t & 63;

  // stage Wa
#pragma unroll
  for (int it = 0; it < 4; ++it) {
    int idx = t + 256 * it;
    reinterpret_cast<float4*>(B_lds)[idx] = reinterpret_cast<const float4*>(Wa)[idx];
  }

  // phase A: agg = ss - ps for 32 nodes (8 per wave), 8-deep chunked gathers
  for (int q = 0; q < 8; ++q) {
    int li = wv * 8 + q;
    int n = m0 + li;
    float aggv = 0.f;
    if (n < N_) {
      float ss = 0.f, ps = 0.f;
      int p0 = __builtin_amdgcn_readfirstlane(csr_off[n]);
      int p1 = __builtin_amdgcn_readfirstlane(csr_off[n + 1]);
      for (int p = p0; p < p1; p += 8) {
        int cnt = p1 - p;
        int idx8[8];
#pragma unroll
        for (int u = 0; u < 8; ++u) idx8[u] = (u < cnt) ? pairs[p + u] : -1;
#pragma unroll
        for (int u = 0; u < 8; ++u) {
          if (idx8[u] >= 0) {
            int e = idx8[u] / 6, a = idx8[u] - e * 6;
            float sv = SB[e * D_ + l];
            float rv = rel_emb_l[rel_list[e] * D_ + l];
            float pv = pos_table[(a + 1) * D_ + l];
            ss += sv; ps = fmaf(rv, pv, ps);
          }
        }
      }
      aggv = ss - ps;
    }
    A_lds[li * 68 + l] = aggv;
  }
  __syncthreads();

  // GEMM: acc = AGG @ Wa + b_lin
  float acc[2][4];
  float4 bl4 = *reinterpret_cast<const float4*>(&bl_[tx * 4]);
#pragma unroll
  for (int i = 0; i < 2; ++i) {
    acc[i][0] = bl4.x; acc[i][1] = bl4.y; acc[i][2] = bl4.z; acc[i][3] = bl4.w;
  }
#pragma unroll 8
  for (int k = 0; k < 64; ++k) {
    float4 b4 = *reinterpret_cast<const float4*>(&B_lds[k * 64 + tx * 4]);
    float a0 = A_lds[(ty * 2 + 0) * 68 + k];
    float a1 = A_lds[(ty * 2 + 1) * 68 + k];
    acc[0][0] = fmaf(a0, b4.x, acc[0][0]); acc[0][1] = fmaf(a0, b4.y, acc[0][1]);
    acc[0][2] = fmaf(a0, b4.z, acc[0][2]); acc[0][3] = fmaf(a0, b4.w, acc[0][3]);
    acc[1][0] = fmaf(a1, b4.x, acc[1][0]); acc[1][1] = fmaf(a1, b4.y, acc[1][1]);
    acc[1][2] = fmaf(a1, b4.z, acc[1][2]); acc[1][3] = fmaf(a1, b4.w, acc[1][3]);
  }
  __syncthreads();

  // out tile -> LDS
#pragma unroll
  for (int i = 0; i < 2; ++i) {
    float4 v = make_float4(acc[i][0], acc[i][1], acc[i][2], acc[i][3]);
    *reinterpret_cast<float4*>(&A_lds[(ty * 2 + i) * 68 + tx * 4]) = v;
  }
  __syncthreads();

  // LN + relu (residual = 0) -> broadcast into h1[n][b][l] for b=0..3
  float g = g_[l], be = be_[l];
#pragma unroll 4
  for (int rr = 0; rr < 8; ++rr) {
    int r = wv * 8 + rr;
    int n = m0 + r;
    float x = A_lds[r * 68 + l];
    float mu = wave_sum(x) * (1.f / 64.f);
    float dx = x - mu;
    float var = wave_sum(dx * dx) * (1.f / 64.f);
    float y = dx * rsqrtf(var + 1e-5f) * g + be;
    float hv = fmaxf(y, 0.f);
    if (n < N_) {
#pragma unroll
      for (int b = 0; b < B_; ++b) h1[(n * B_ + b) * D_ + l] = hv;
    }
  }
}

// ---------- dirty propagation (1 hop) ----------

__global__ void copy_dirty_kernel(const int* __restrict__ src, int* __restrict__ dst) {
  int n = blockIdx.x * blockDim.x + threadIdx.x;
  if (n < N_) dst[n] = src[n];
}

__global__ void edge_prop_kernel(const int* __restrict__ edge_list,
                                 const int* __restrict__ dirty_l, int* __restrict__ dirty_n,
                                 int* __restrict__ elist, int* __restrict__ ctrs) {
  int e = blockIdx.x * blockDim.x + threadIdx.x;
  if (e >= E_) return;
  int mem[A_];
  int m = 0;
#pragma unroll
  for (int a = 0; a < A_; ++a) {
    mem[a] = edge_list[e * A_ + a];
    if (mem[a]) m |= dirty_l[mem[a]];
  }
  if (m) {
#pragma unroll
    for (int a = 0; a < A_; ++a)
      if (mem[a]) atomicOr(&dirty_n[mem[a]], m);
    int s = atomicAdd(&ctrs[0], 1);
    elist[s] = e | (m << 16);
  }
}

// ---------- per-dirty-edge correction: Scorr = rel ⊙ Σ_members δ0 (from seed table) ----------

__global__ __launch_bounds__(256) void scorr_kernel(
    const int* __restrict__ elist, const int* __restrict__ edge_list,
    const int* __restrict__ rel_list, const float* __restrict__ rel_emb_l,
    const int* __restrict__ seednode, const float* __restrict__ seedvec,
    float* __restrict__ Scorr, int* __restrict__ emap, int* __restrict__ ctrs) {
  int cnt = ctrs[0];
  int w = blockIdx.x * 4 + (threadIdx.x >> 6);
  int nw = gridDim.x * 4;
  int lane = threadIdx.x & 63;
  for (int i = w; i < cnt; i += nw) {
    int pk = elist[i];
    int e = pk & 0xFFFF, m = pk >> 16;
    float rel = rel_emb_l[rel_list[e] * D_ + lane];
    int mem[A_];
#pragma unroll
    for (int a = 0; a < A_; ++a) mem[a] = edge_list[e * A_ + a];
#pragma unroll
    for (int b = 0; b < B_; ++b) {
      if ((m >> b) & 1) {
        float s = 0.f;
#pragma unroll
        for (int a = 0; a < A_; ++a) {
          if (mem[a]) {
#pragma unroll
            for (int j = 0; j < A_; ++j) {
              int slot = b * A_ + j;
              if (seednode[slot] == mem[a]) s += seedvec[slot * D_ + lane];
            }
          }
        }
        int slot = 0;
        if (lane == 0) slot = atomicAdd(&ctrs[1], 1);
        slot = __shfl(slot, 0);
        if (slot < SC_CAP) {
          Scorr[slot * D_ + lane] = rel * s;
          if (lane == 0) emap[e * B_ + b] = slot + 1;
        }
      }
    }
  }
}

__global__ void compact_kernel(const int* __restrict__ dirty_n, int* __restrict__ nlist,
                               int* __restrict__ ctrs) {
  int n = blockIdx.x * blockDim.x + threadIdx.x;
  if (n >= N_) return;
  int m = dirty_n[n];
  if (m) {
    int s = atomicAdd(&ctrs[2], 1);
    nlist[s] = n | (m << 16);
  }
}

// ---------- exact recompute of dirty layer-1 rows -> overwrite h1 ----------

__global__ __launch_bounds__(256) void corr_kernel(
    const int* __restrict__ nlist, const int* __restrict__ ctrs,
    const int* __restrict__ csr_off, const int* __restrict__ pairs,
    const int* __restrict__ rel_list, const float* __restrict__ pos_table,
    const float* __restrict__ rel_emb_l, const float* __restrict__ SB,
    const float* __restrict__ Scorr, const int* __restrict__ emap,
    const int* __restrict__ seednode, const float* __restrict__ seedvec,
    float* __restrict__ h1,
    const float* __restrict__ Wa, const float* __restrict__ Ws,
    const float* __restrict__ bl_, const float* __restrict__ g_,
    const float* __restrict__ be_) {
  __shared__ float WaL[64 * 64];
  __shared__ float WsL[64 * 64];
  int t = threadIdx.x;
#pragma unroll
  for (int it = 0; it < 4; ++it) {
    int idx = t + 256 * it;
    reinterpret_cast<float4*>(WaL)[idx] = reinterpret_cast<const float4*>(Wa)[idx];
    reinterpret_cast<float4*>(WsL)[idx] = reinterpret_cast<const float4*>(Ws)[idx];
  }
  __syncthreads();
  int cntn = ctrs[2];
  int w = blockIdx.x * 4 + (t >> 6);
  int nw = gridDim.x * 4;
  int lane = t & 63;
  float blv = bl_[lane], gv = g_[lane], bev = be_[lane];
  for (int i = w; i < cntn; i += nw) {
    int pk = nlist[i];
    int n = pk & 0xFFFF, m = pk >> 16;
    int p0 = csr_off[n], p1 = csr_off[n + 1];
#pragma unroll
    for (int b = 0; b < B_; ++b) {
      if ((m >> b) & 1) {
        // h0[n,b] from seed table
        float hv = 0.f;
#pragma unroll
        for (int j = 0; j < A_; ++j) {
          int slot = b * A_ + j;
          if (seednode[slot] == n) hv += seedvec[slot * D_ + lane];
        }
        float ss = 0.f, rs = 0.f, ps = 0.f;
        for (int p = p0; p < p1; ++p) {
          int ii = pairs[p];
          int e = ii / 6, a = ii - e * 6;
          float sv = SB[e * D_ + lane];
          int ei = emap[e * B_ + b];
          if (ei) sv += Scorr[(ei - 1) * D_ + lane];
          float rv = rel_emb_l[rel_list[e] * D_ + lane];
          float pv = pos_table[(a + 1) * D_ + lane];
          ss += sv; rs += rv; ps = fmaf(rv, pv, ps);
        }
        float aggv = ss - hv * rs - ps;
        float out = blv;
#pragma unroll 16
        for (int k = 0; k < 64; ++k) {
          out = fmaf(rlane(aggv, k), WaL[k * 64 + lane], out);
          out = fmaf(rlane(hv, k), WsL[k * 64 + lane], out);
        }
        float mu = wave_sum(out) * (1.f / 64.f);
        float dx = out - mu;
        float var = wave_sum(dx * dx) * (1.f / 64.f);
        float y = dx * rsqrtf(var + 1e-5f) * gv + bev;
        h1[(n * B_ + b) * D_ + lane] = fmaxf(y, 0.f) + hv;
      }
    }
  }
}

// ---------- layer-2 only at candidates, fused with scoring MLP ----------
// wave = (b,c): n = cand; compute agg2 with inline per-edge S; matvec; LN; relu; +h1;
// then score = relu([h2|q] @ W1 + b1) @ W2 + b2.

__global__ __launch_bounds__(512) void cand_kernel(
    const int* __restrict__ ents, const int* __restrict__ meta,
    const int* __restrict__ csr_off, const int* __restrict__ pairs,
    const int* __restrict__ edge_list, const int* __restrict__ rel_list,
    const float* __restrict__ pos_table, const float* __restrict__ rel_emb_l,
    const float* __restrict__ h1, const float* __restrict__ query_emb,
    const float* __restrict__ Wa, const float* __restrict__ Ws,
    const float* __restrict__ bl_, const float* __restrict__ g_,
    const float* __restrict__ be_,
    const float* __restrict__ W1, const float* __restrict__ b1,
    const float* __restrict__ W2, const float* __restrict__ b2,
    float* __restrict__ out) {
  __shared__ float WaL[64 * 64];
  __shared__ float WsL[64 * 64];
  int t = threadIdx.x;
#pragma unroll
  for (int it = 0; it < 2; ++it) {
    int idx = t + 512 * it;
    reinterpret_cast<float4*>(WaL)[idx] = reinterpret_cast<const float4*>(Wa)[idx];
    reinterpret_cast<float4*>(WsL)[idx] = reinterpret_cast<const float4*>(Ws)[idx];
  }
  __syncthreads();
  int w = blockIdx.x * 8 + (t >> 6);
  int lane = t & 63;
  if (w >= B_ * C_) return;
  int b = w / C_;
  int c = w - b * C_;
  int psn = meta[b];
  int qr = meta[B_ + b];
  int n = ents[(b * C_ + c) * A_ + psn];

  float h1v = h1[(n * B_ + b) * D_ + lane];
  int p0 = __builtin_amdgcn_readfirstlane(csr_off[n]);
  int p1 = __builtin_amdgcn_readfirstlane(csr_off[n + 1]);
  float aggv = 0.f;
  for (int p = p0; p < p1; ++p) {
    int ii = pairs[p];
    int e = ii / 6, a = ii - e * 6;
    float rel = rel_emb_l[rel_list[e] * D_ + lane];
    float s = 0.f;
#pragma unroll
    for (int a2 = 0; a2 < A_; ++a2) {
      int m2 = edge_list[e * A_ + a2];
      if (m2) s += h1[(m2 * B_ + b) * D_ + lane] + pos_table[(a2 + 1) * D_ + lane];
    }
    // S_e - (h1v + pos_a)*rel
    aggv = fmaf(s - (h1v + pos_table[(a + 1) * D_ + lane]), rel, aggv);
  }

  float outv = bl_[lane];
#pragma unroll 16
  for (int k = 0; k < 64; ++k) {
    outv = fmaf(rlane(aggv, k), WaL[k * 64 + lane], outv);
    outv = fmaf(rlane(h1v, k), WsL[k * 64 + lane], outv);
  }
  float mu = wave_sum(outv) * (1.f / 64.f);
  float dx = outv - mu;
  float var = wave_sum(dx * dx) * (1.f / 64.f);
  float y = dx * rsqrtf(var + 1e-5f) * g_[lane] + be_[lane];
  float h2v = fmaxf(y, 0.f) + h1v;

  float qv = query_emb[qr * D_ + lane];
  float hid0 = b1[lane];
  float hid1 = b1[D_ + lane];
#pragma unroll
  for (int k = 0; k < D_; ++k) {
    float f = rlane(h2v, k);
    hid0 = fmaf(f, W1[k * FEAT_ + lane], hid0);
    hid1 = fmaf(f, W1[k * FEAT_ + D_ + lane], hid1);
  }
#pragma unroll
  for (int k = 0; k < D_; ++k) {
    float q = rlane(qv, k);
    hid0 = fmaf(q, W1[(D_ + k) * FEAT_ + lane], hid0);
    hid1 = fmaf(q, W1[(D_ + k) * FEAT_ + D_ + lane], hid1);
  }
  float accs = fmaxf(hid0, 0.f) * W2[lane] + fmaxf(hid1, 0.f) * W2[D_ + lane];
  accs = wave_sum(accs);
  if (lane == 0) out[w] = accs + b2[0];
}

// ---------- launch ----------

extern "C" void kernel_launch(void* const* d_in, const int* in_sizes, int n_in,
                              void* d_out, int out_size, void* d_ws, size_t ws_size,
                              hipStream_t stream) {
  const int* r_idx = (const int*)d_in[0];
  const int* ents = (const int*)d_in[1];
  const int* arity = (const int*)d_in[2];
  const int* edge_list = (const int*)d_in[3];
  const int* rel_list = (const int*)d_in[4];
  const float* pos_table = (const float*)d_in[5];
  const float* query_emb = (const float*)d_in[6];
  const float* rel_emb = (const float*)d_in[7];
  const float* W_agg = (const float*)d_in[8];
  const float* W_self = (const float*)d_in[9];
  const float* b_lin = (const float*)d_in[10];
  const float* ln_g = (const float*)d_in[11];
  const float* ln_b = (const float*)d_in[12];
  const float* W1 = (const float*)d_in[13];
  const float* b1 = (const float*)d_in[14];
  const float* W2 = (const float*)d_in[15];
  const float* b2 = (const float*)d_in[16];
  float* out = (float*)d_out;

  char* ws = (char*)d_ws;
  // layout (bytes, generous alignment)
  float* h1      = (float*)(ws + 0);           // 20,481,024
  float* SB      = (float*)(ws + 20500000);    //  7,680,000
  float* Scorr   = (float*)(ws + 28200000);    //  2,097,152 (SC_CAP*256)
  int* emap      = (int*)(ws + 30300000);      //    480,000
  int* cnt       = (int*)(ws + 30800000);      //     80,008
  int* csr_off   = (int*)(ws + 30900000);      //     80,008
  int* pairs     = (int*)(ws + 31000000);      //    720,064
  int* dirtyA    = (int*)(ws + 31800000);      //     80,004
  int* dirtyB    = (int*)(ws + 31900000);      //     80,004
  int* elist     = (int*)(ws + 32000000);      //    120,000
  int* nlist     = (int*)(ws + 32200000);      //     80,004
  int* seednode  = (int*)(ws + 32300000);      //         96
  float* seedvec = (float*)(ws + 32300096);    //      6,144
  int* ctrs      = (int*)(ws + 32306240);      //         64
  int* meta      = (int*)(ws + 32306304);      //         32
  if (ws_size < 32306336) return;  // insufficient scratch; output stays poisoned

  hipMemsetAsync(cnt, 0, (N_ + 1) * sizeof(int), stream);
  hipMemsetAsync(dirtyA, 0, N_ * sizeof(int), stream);
  hipMemsetAsync(emap, 0, E_ * B_ * sizeof(int), stream);
  hipMemsetAsync(ctrs, 0, 64, stream);

  init_kernel<<<B_, 256, 0, stream>>>(r_idx, ents, arity, pos_table, query_emb,
                                      seednode, seedvec, dirtyA, meta);
  count_kernel<<<(E_ * A_ + 255) / 256, 256, 0, stream>>>(edge_list, cnt);
  scan_kernel<<<1, SCAN_T, 0, stream>>>(cnt, csr_off);
  fill_kernel<<<(E_ * A_ + 255) / 256, 256, 0, stream>>>(edge_list, cnt, pairs);

  const float* rel0 = rel_emb;                 // layer 0
  const float* rel1 = rel_emb + R_ * D_;       // layer 1

  // ----- layer 0 (batch-collapsed + exact 1-hop correction) -----
  sb0_kernel<<<E_ / 8, 512, 0, stream>>>(edge_list, rel_list, pos_table, rel0, SB);
  mainL0_kernel<<<(N_ + 31) / 32, 256, 0, stream>>>(
      csr_off, pairs, rel_list, pos_table, rel0, SB, h1,
      W_agg, b_lin, ln_g, ln_b);
  copy_dirty_kernel<<<(N_ + 255) / 256, 256, 0, stream>>>(dirtyA, dirtyB);
  edge_prop_kernel<<<(E_ + 255) / 256, 256, 0, stream>>>(edge_list, dirtyA, dirtyB,
                                                         elist, ctrs);
  scorr_kernel<<<64, 256, 0, stream>>>(elist, edge_list, rel_list, rel0,
                                       seednode, seedvec, Scorr, emap, ctrs);
  compact_kernel<<<(N_ + 255) / 256, 256, 0, stream>>>(dirtyB, nlist, ctrs);
  corr_kernel<<<128, 256, 0, stream>>>(nlist, ctrs, csr_off, pairs, rel_list,
                                       pos_table, rel0, SB, Scorr, emap,
                                       seednode, seedvec, h1,
                                       W_agg, W_self, b_lin, ln_g, ln_b);

  // ----- layer 1 only at candidates, fused with scoring -----
  cand_kernel<<<(B_ * C_ + 7) / 8, 512, 0, stream>>>(
      ents, meta, csr_off, pairs, edge_list, rel_list, pos_table, rel1,
      h1, query_emb,
      W_agg + D_ * D_, W_self + D_ * D_, b_lin + D_, ln_g + D_, ln_b + D_,
      W1, b1, W2, b2, out);

  (void)in_sizes; (void)n_in; (void)out_size;
}

// Round 7
// 147.412 us; speedup vs baseline: 2.4056x; 1.1683x over previous
//
#include <hip/hip_runtime.h>

#define D_ 64
#define L_ 2
#define R_ 50
#define N_ 20001
#define A_ 6
#define E_ 30000
#define B_ 4
#define C_ 500
#define FEAT_ 128
#define SC_CAP 8192

__device__ __forceinline__ float rlane(float v, int k) {
  return __builtin_bit_cast(float, __builtin_amdgcn_readlane(__builtin_bit_cast(int, v), k));
}
__device__ __forceinline__ float wave_sum(float v) {
#pragma unroll
  for (int off = 32; off; off >>= 1) v += __shfl_xor(v, off);
  return v;
}
// runtime-index select from 6 named regs (avoids scratch spill of reg arrays)
__device__ __forceinline__ float sel6(float p0, float p1, float p2, float p3,
                                      float p4, float p5, int a) {
  float r = p0;
  r = (a == 1) ? p1 : r; r = (a == 2) ? p2 : r; r = (a == 3) ? p3 : r;
  r = (a == 4) ? p4 : r; r = (a == 5) ? p5 : r;
  return r;
}

// ---------- init: pos_search + seed table + dirty marks ----------

__global__ void init_kernel(const int* __restrict__ r_idx, const int* __restrict__ ents,
                            const int* __restrict__ arity,
                            const float* __restrict__ pos_table,
                            const float* __restrict__ query_emb,
                            int* __restrict__ seednode, float* __restrict__ seedvec,
                            int* __restrict__ dirtyA, int* __restrict__ dirty_n,
                            int* __restrict__ meta) {
  int b = blockIdx.x, t = threadIdx.x;
  __shared__ int diff[A_];
  if (t < A_) diff[t] = 0;
  __syncthreads();
#pragma unroll
  for (int a = 0; a < A_; ++a) {
    int v0 = ents[(b * C_) * A_ + a];
    int dd = 0;
    for (int c = t; c < C_; c += 256) dd |= (ents[(b * C_ + c) * A_ + a] != v0);
    if (dd) diff[a] = 1;
  }
  __syncthreads();
  int ps = 0;
  for (int a = A_ - 1; a >= 0; --a) if (diff[a]) ps = a;
  int qr = r_idx[b * C_];
  if (t == 0) { meta[b] = ps; meta[B_ + b] = qr; }
  int ar = arity[b * C_];
  int lane = t & 63;
  for (int a = (t >> 6); a < A_; a += 4) {
    int slot = b * A_ + a;
    if (a < ar && a != ps) {
      int n = ents[(b * C_) * A_ + a];
      seedvec[slot * D_ + lane] = query_emb[qr * D_ + lane] + pos_table[(a + 1) * D_ + lane];
      if (lane == 0) {
        seednode[slot] = n;
        atomicOr(&dirtyA[n], 1 << b);
        atomicOr(&dirty_n[n], 1 << b);
      }
    } else {
      if (lane == 0) seednode[slot] = 0;
    }
  }
}

// ---------- CSR build (+ per-edge valid mask) ----------

__global__ void count_kernel(const int* __restrict__ edge_list, int* __restrict__ cnt,
                             int* __restrict__ emask) {
  int i = blockIdx.x * blockDim.x + threadIdx.x;
  if (i >= E_ * A_) return;
  int n = edge_list[i];
  if (n) {
    atomicAdd(&cnt[n], 1);
    atomicOr(&emask[i / A_], 1 << (i % A_));
  }
}

#define SCAN_T 1024
#define CHUNK 20
__global__ void scan_kernel(int* __restrict__ cnt, int* __restrict__ off) {
  __shared__ int part[SCAN_T];
  int t = threadIdx.x;
  int base = t * CHUNK;
  int v[CHUNK];
  int s = 0;
#pragma unroll
  for (int i = 0; i < CHUNK; ++i) {
    int idx = base + i;
    v[i] = (idx < N_) ? cnt[idx] : 0;
    s += v[i];
  }
  part[t] = s;
  __syncthreads();
  for (int d = 1; d < SCAN_T; d <<= 1) {
    int x = part[t];
    int y = (t >= d) ? part[t - d] : 0;
    __syncthreads();
    part[t] = x + y;
    __syncthreads();
  }
  int run = (t == 0) ? 0 : part[t - 1];
#pragma unroll
  for (int i = 0; i < CHUNK; ++i) {
    int idx = base + i;
    if (idx < N_) {
      off[idx] = run;
      cnt[idx] = run;  // cursor for fill
      run += v[i];
    }
  }
  if (t == SCAN_T - 1) off[N_] = part[SCAN_T - 1];
}

__global__ void fill_kernel(const int* __restrict__ edge_list, int* __restrict__ cur,
                            int* __restrict__ pairs) {
  int i = blockIdx.x * blockDim.x + threadIdx.x;
  if (i >= E_ * A_) return;
  int n = edge_list[i];
  if (n) {
    int p = atomicAdd(&cur[n], 1);
    pairs[p] = i;
  }
}

// ---------- layer-0 batch-collapsed node update -> H1[n][64] ----------
// agg[n] = sum_pairs rel_e ⊙ (possum_e - pos_a);  H1 = relu(LN(agg@Wa + b_lin))

__global__ __launch_bounds__(256) void mainL0_kernel(
    const int* __restrict__ csr_off, const int* __restrict__ pairs,
    const int* __restrict__ rel_list, const int* __restrict__ emask,
    const float* __restrict__ pos_table, const float* __restrict__ rel_emb_l,
    float* __restrict__ H1,
    const float* __restrict__ Wa, const float* __restrict__ bl_,
    const float* __restrict__ g_, const float* __restrict__ be_) {
  __shared__ float A_lds[32 * 68];
  __shared__ float B_lds[64 * 64];
  int t = threadIdx.x;
  int m0 = blockIdx.x * 32;
  int ty = t >> 4, tx = t & 15;
  int wv = t >> 6, l = t & 63;

  float pv0 = pos_table[1 * D_ + l], pv1 = pos_table[2 * D_ + l];
  float pv2 = pos_table[3 * D_ + l], pv3 = pos_table[4 * D_ + l];
  float pv4 = pos_table[5 * D_ + l], pv5 = pos_table[6 * D_ + l];

#pragma unroll
  for (int it = 0; it < 4; ++it) {
    int idx = t + 256 * it;
    reinterpret_cast<float4*>(B_lds)[idx] = reinterpret_cast<const float4*>(Wa)[idx];
  }

  for (int q = 0; q < 8; ++q) {
    int li = wv * 8 + q;
    int n = m0 + li;
    float aggv = 0.f;
    if (n < N_) {
      int p0 = __builtin_amdgcn_readfirstlane(csr_off[n]);
      int p1 = __builtin_amdgcn_readfirstlane(csr_off[n + 1]);
      for (int p = p0; p < p1; p += 8) {
        int cnt = p1 - p;
        int idx8[8];
#pragma unroll
        for (int u = 0; u < 8; ++u) idx8[u] = (u < cnt) ? pairs[p + u] : -1;
#pragma unroll
        for (int u = 0; u < 8; ++u) {
          if (idx8[u] >= 0) {
            int e = idx8[u] / 6, a = idx8[u] - e * 6;
            int msk = emask[e];
            float rel = rel_emb_l[rel_list[e] * D_ + l];
            float possum = 0.f;
            possum += (msk & 1) ? pv0 : 0.f;
            possum += (msk & 2) ? pv1 : 0.f;
            possum += (msk & 4) ? pv2 : 0.f;
            possum += (msk & 8) ? pv3 : 0.f;
            possum += (msk & 16) ? pv4 : 0.f;
            possum += (msk & 32) ? pv5 : 0.f;
            float pa = sel6(pv0, pv1, pv2, pv3, pv4, pv5, a);
            aggv = fmaf(rel, possum - pa, aggv);
          }
        }
      }
    }
    A_lds[li * 68 + l] = aggv;
  }
  __syncthreads();

  float acc[2][4];
  float4 bl4 = *reinterpret_cast<const float4*>(&bl_[tx * 4]);
#pragma unroll
  for (int i = 0; i < 2; ++i) {
    acc[i][0] = bl4.x; acc[i][1] = bl4.y; acc[i][2] = bl4.z; acc[i][3] = bl4.w;
  }
#pragma unroll 8
  for (int k = 0; k < 64; ++k) {
    float4 b4 = *reinterpret_cast<const float4*>(&B_lds[k * 64 + tx * 4]);
    float a0 = A_lds[(ty * 2 + 0) * 68 + k];
    float a1 = A_lds[(ty * 2 + 1) * 68 + k];
    acc[0][0] = fmaf(a0, b4.x, acc[0][0]); acc[0][1] = fmaf(a0, b4.y, acc[0][1]);
    acc[0][2] = fmaf(a0, b4.z, acc[0][2]); acc[0][3] = fmaf(a0, b4.w, acc[0][3]);
    acc[1][0] = fmaf(a1, b4.x, acc[1][0]); acc[1][1] = fmaf(a1, b4.y, acc[1][1]);
    acc[1][2] = fmaf(a1, b4.z, acc[1][2]); acc[1][3] = fmaf(a1, b4.w, acc[1][3]);
  }
  __syncthreads();
#pragma unroll
  for (int i = 0; i < 2; ++i) {
    float4 v = make_float4(acc[i][0], acc[i][1], acc[i][2], acc[i][3]);
    *reinterpret_cast<float4*>(&A_lds[(ty * 2 + i) * 68 + tx * 4]) = v;
  }
  __syncthreads();

  float g = g_[l], be = be_[l];
#pragma unroll 4
  for (int rr = 0; rr < 8; ++rr) {
    int r = wv * 8 + rr;
    int n = m0 + r;
    float x = A_lds[r * 68 + l];
    float mu = wave_sum(x) * (1.f / 64.f);
    float dx = x - mu;
    float var = wave_sum(dx * dx) * (1.f / 64.f);
    float y = dx * rsqrtf(var + 1e-5f) * g + be;
    if (n < N_) H1[n * D_ + l] = fmaxf(y, 0.f);
  }
}

// ---------- fused edge-prop + Scorr (wave per edge) ----------
// Scorr[(e,b)] = rel_e ⊙ Σ_members δ0[member,b] (seed table)

__global__ __launch_bounds__(256) void eps_kernel(
    const int* __restrict__ edge_list, const int* __restrict__ rel_list,
    const float* __restrict__ rel_emb_l,
    const int* __restrict__ dirtyA, int* __restrict__ dirty_n,
    const int* __restrict__ seednode, const float* __restrict__ seedvec,
    float* __restrict__ Scorr, int* __restrict__ emap, int* __restrict__ ctrs) {
  int e = blockIdx.x * 4 + (threadIdx.x >> 6);
  int lane = threadIdx.x & 63;
  if (e >= E_) return;
  int mem[A_];
  int m = 0;
#pragma unroll
  for (int a = 0; a < A_; ++a) {
    mem[a] = edge_list[e * A_ + a];
    if (mem[a]) m |= dirtyA[mem[a]];
  }
  if (!m) return;
#pragma unroll
  for (int a = 0; a < A_; ++a)
    if (lane == a && mem[a]) atomicOr(&dirty_n[mem[a]], m);
  float rel = rel_emb_l[rel_list[e] * D_ + lane];
#pragma unroll
  for (int b = 0; b < B_; ++b) {
    if ((m >> b) & 1) {
      float s = 0.f;
#pragma unroll
      for (int a = 0; a < A_; ++a) {
        if (mem[a]) {
#pragma unroll
          for (int j = 0; j < A_; ++j) {
            int sl = b * A_ + j;
            if (seednode[sl] == mem[a]) s += seedvec[sl * D_ + lane];
          }
        }
      }
      int slot = 0;
      if (lane == 0) slot = atomicAdd(&ctrs[1], 1);
      slot = __shfl(slot, 0);
      if (slot < SC_CAP) {
        Scorr[slot * D_ + lane] = rel * s;
        if (lane == 0) emap[e * B_ + b] = slot + 1;
      }
    }
  }
}

// ---------- exact recompute of dirty layer-1 rows -> Hcorr (+cmap), self-compacting ----------

__global__ __launch_bounds__(256) void corr_kernel(
    const int* __restrict__ csr_off, const int* __restrict__ pairs,
    const int* __restrict__ rel_list, const int* __restrict__ emask,
    const float* __restrict__ pos_table, const float* __restrict__ rel_emb_l,
    const float* __restrict__ Scorr, const int* __restrict__ emap,
    const int* __restrict__ dirty_n,
    const int* __restrict__ seednode, const float* __restrict__ seedvec,
    int* __restrict__ cmap, float* __restrict__ Hcorr,
    const float* __restrict__ Wa, const float* __restrict__ Ws,
    const float* __restrict__ bl_, const float* __restrict__ g_,
    const float* __restrict__ be_, int* __restrict__ ctrs) {
  __shared__ float WaL[64 * 64];
  __shared__ float WsL[64 * 64];
  int t = threadIdx.x;
  int wv = t >> 6, lane = t & 63;
  int n = blockIdx.x * 4 + wv;
  int m = (n < N_) ? dirty_n[n] : 0;
  if (__syncthreads_or(m) == 0) return;  // whole block clean
#pragma unroll
  for (int it = 0; it < 4; ++it) {
    int idx = t + 256 * it;
    reinterpret_cast<float4*>(WaL)[idx] = reinterpret_cast<const float4*>(Wa)[idx];
    reinterpret_cast<float4*>(WsL)[idx] = reinterpret_cast<const float4*>(Ws)[idx];
  }
  __syncthreads();
  if (!m) return;

  float pv0 = pos_table[1 * D_ + lane], pv1 = pos_table[2 * D_ + lane];
  float pv2 = pos_table[3 * D_ + lane], pv3 = pos_table[4 * D_ + lane];
  float pv4 = pos_table[5 * D_ + lane], pv5 = pos_table[6 * D_ + lane];

  int slot = 0;
  if (lane == 0) slot = atomicAdd(&ctrs[2], 1);
  slot = __shfl(slot, 0);
  if (lane == 0) cmap[n] = slot;

  float blv = bl_[lane], gv = g_[lane], bev = be_[lane];
  int p0 = csr_off[n], p1 = csr_off[n + 1];
  float ss0 = 0.f, ss1 = 0.f, ss2 = 0.f, ss3 = 0.f;
  float rs = 0.f, ps = 0.f;
  for (int p = p0; p < p1; ++p) {
    int ii = pairs[p];
    int e = ii / 6, a = ii - e * 6;
    int msk = emask[e];
    float rel = rel_emb_l[rel_list[e] * D_ + lane];
    float possum = 0.f;
    possum += (msk & 1) ? pv0 : 0.f;
    possum += (msk & 2) ? pv1 : 0.f;
    possum += (msk & 4) ? pv2 : 0.f;
    possum += (msk & 8) ? pv3 : 0.f;
    possum += (msk & 16) ? pv4 : 0.f;
    possum += (msk & 32) ? pv5 : 0.f;
    float base = rel * possum;
    rs += rel;
    ps = fmaf(rel, sel6(pv0, pv1, pv2, pv3, pv4, pv5, a), ps);
    if ((m >> 0) & 1) { int ei = emap[e * B_ + 0]; ss0 += base + (ei ? Scorr[(ei - 1) * D_ + lane] : 0.f); }
    if ((m >> 1) & 1) { int ei = emap[e * B_ + 1]; ss1 += base + (ei ? Scorr[(ei - 1) * D_ + lane] : 0.f); }
    if ((m >> 2) & 1) { int ei = emap[e * B_ + 2]; ss2 += base + (ei ? Scorr[(ei - 1) * D_ + lane] : 0.f); }
    if ((m >> 3) & 1) { int ei = emap[e * B_ + 3]; ss3 += base + (ei ? Scorr[(ei - 1) * D_ + lane] : 0.f); }
  }
#pragma unroll
  for (int b = 0; b < B_; ++b) {
    if ((m >> b) & 1) {
      float ssb = (b == 0) ? ss0 : (b == 1) ? ss1 : (b == 2) ? ss2 : ss3;
      float hv = 0.f;
#pragma unroll
      for (int j = 0; j < A_; ++j) {
        int sl = b * A_ + j;
        if (seednode[sl] == n) hv += seedvec[sl * D_ + lane];
      }
      float aggv = ssb - hv * rs - ps;
      float out = blv;
#pragma unroll 16
      for (int k = 0; k < 64; ++k) {
        out = fmaf(rlane(aggv, k), WaL[k * 64 + lane], out);
        out = fmaf(rlane(hv, k), WsL[k * 64 + lane], out);
      }
      float mu = wave_sum(out) * (1.f / 64.f);
      float dx = out - mu;
      float var = wave_sum(dx * dx) * (1.f / 64.f);
      float y = dx * rsqrtf(var + 1e-5f) * gv + bev;
      Hcorr[(slot * B_ + b) * D_ + lane] = fmaxf(y, 0.f) + hv;
    }
  }
}

// ---------- layer-2 at candidates only, fused with scoring MLP (h1 via overlay) ----------

__global__ __launch_bounds__(512) void cand_kernel(
    const int* __restrict__ ents, const int* __restrict__ meta,
    const int* __restrict__ csr_off, const int* __restrict__ pairs,
    const int* __restrict__ edge_list, const int* __restrict__ rel_list,
    const float* __restrict__ pos_table, const float* __restrict__ rel_emb_l,
    const float* __restrict__ H1, const float* __restrict__ Hcorr,
    const int* __restrict__ cmap, const int* __restrict__ dirty_n,
    const float* __restrict__ query_emb,
    const float* __restrict__ Wa, const float* __restrict__ Ws,
    const float* __restrict__ bl_, const float* __restrict__ g_,
    const float* __restrict__ be_,
    const float* __restrict__ W1, const float* __restrict__ b1,
    const float* __restrict__ W2, const float* __restrict__ b2,
    float* __restrict__ out) {
  __shared__ float WaL[64 * 64];
  __shared__ float WsL[64 * 64];
  int t = threadIdx.x;
#pragma unroll
  for (int it = 0; it < 2; ++it) {
    int idx = t + 512 * it;
    reinterpret_cast<float4*>(WaL)[idx] = reinterpret_cast<const float4*>(Wa)[idx];
    reinterpret_cast<float4*>(WsL)[idx] = reinterpret_cast<const float4*>(Ws)[idx];
  }
  __syncthreads();
  int w = blockIdx.x * 8 + (t >> 6);
  int lane = t & 63;
  if (w >= B_ * C_) return;
  int b = w / C_;
  int c = w - b * C_;
  int psn = meta[b];
  int qr = meta[B_ + b];
  int n = ents[(b * C_ + c) * A_ + psn];

  float pv0 = pos_table[1 * D_ + lane], pv1 = pos_table[2 * D_ + lane];
  float pv2 = pos_table[3 * D_ + lane], pv3 = pos_table[4 * D_ + lane];
  float pv4 = pos_table[5 * D_ + lane], pv5 = pos_table[6 * D_ + lane];

  float h1v = H1[n * D_ + lane];
  if ((dirty_n[n] >> b) & 1) h1v = Hcorr[(cmap[n] * B_ + b) * D_ + lane];

  int p0 = __builtin_amdgcn_readfirstlane(csr_off[n]);
  int p1 = __builtin_amdgcn_readfirstlane(csr_off[n + 1]);
  float aggv = 0.f;
  for (int p = p0; p < p1; ++p) {
    int ii = pairs[p];
    int e = ii / 6, a = ii - e * 6;
    float rel = rel_emb_l[rel_list[e] * D_ + lane];
    float s = 0.f;
#pragma unroll
    for (int a2 = 0; a2 < A_; ++a2) {
      int m2 = edge_list[e * A_ + a2];
      if (m2) {
        float hm = H1[m2 * D_ + lane];
        if ((dirty_n[m2] >> b) & 1) hm = Hcorr[(cmap[m2] * B_ + b) * D_ + lane];
        float pa2 = sel6(pv0, pv1, pv2, pv3, pv4, pv5, a2);
        s += hm + pa2;
      }
    }
    float pa = sel6(pv0, pv1, pv2, pv3, pv4, pv5, a);
    aggv = fmaf(s - h1v - pa, rel, aggv);
  }

  float outv = bl_[lane];
#pragma unroll 16
  for (int k = 0; k < 64; ++k) {
    outv = fmaf(rlane(aggv, k), WaL[k * 64 + lane], outv);
    outv = fmaf(rlane(h1v, k), WsL[k * 64 + lane], outv);
  }
  float mu = wave_sum(outv) * (1.f / 64.f);
  float dx = outv - mu;
  float var = wave_sum(dx * dx) * (1.f / 64.f);
  float y = dx * rsqrtf(var + 1e-5f) * g_[lane] + be_[lane];
  float h2v = fmaxf(y, 0.f) + h1v;

  float qv = query_emb[qr * D_ + lane];
  float hid0 = b1[lane];
  float hid1 = b1[D_ + lane];
#pragma unroll
  for (int k = 0; k < D_; ++k) {
    float f = rlane(h2v, k);
    hid0 = fmaf(f, W1[k * FEAT_ + lane], hid0);
    hid1 = fmaf(f, W1[k * FEAT_ + D_ + lane], hid1);
  }
#pragma unroll
  for (int k = 0; k < D_; ++k) {
    float q = rlane(qv, k);
    hid0 = fmaf(q, W1[(D_ + k) * FEAT_ + lane], hid0);
    hid1 = fmaf(q, W1[(D_ + k) * FEAT_ + D_ + lane], hid1);
  }
  float accs = fmaxf(hid0, 0.f) * W2[lane] + fmaxf(hid1, 0.f) * W2[D_ + lane];
  accs = wave_sum(accs);
  if (lane == 0) out[w] = accs + b2[0];
}

// ---------- launch ----------

extern "C" void kernel_launch(void* const* d_in, const int* in_sizes, int n_in,
                              void* d_out, int out_size, void* d_ws, size_t ws_size,
                              hipStream_t stream) {
  const int* r_idx = (const int*)d_in[0];
  const int* ents = (const int*)d_in[1];
  const int* arity = (const int*)d_in[2];
  const int* edge_list = (const int*)d_in[3];
  const int* rel_list = (const int*)d_in[4];
  const float* pos_table = (const float*)d_in[5];
  const float* query_emb = (const float*)d_in[6];
  const float* rel_emb = (const float*)d_in[7];
  const float* W_agg = (const float*)d_in[8];
  const float* W_self = (const float*)d_in[9];
  const float* b_lin = (const float*)d_in[10];
  const float* ln_g = (const float*)d_in[11];
  const float* ln_b = (const float*)d_in[12];
  const float* W1 = (const float*)d_in[13];
  const float* b1 = (const float*)d_in[14];
  const float* W2 = (const float*)d_in[15];
  const float* b2 = (const float*)d_in[16];
  float* out = (float*)d_out;

  char* ws = (char*)d_ws;
  // layout (bytes)
  float* H1      = (float*)(ws + 0);           //  5,120,256
  float* Hcorr   = (float*)(ws + 5120512);     // 20,481,024 (full-capacity overlay)
  float* Scorr   = (float*)(ws + 25601536);    //  2,097,152
  int* cmap      = (int*)(ws + 27698688);      //     80,004
  int* seednode  = (int*)(ws + 27778816);      //         96
  float* seedvec = (float*)(ws + 27778912);    //      6,144
  int* meta      = (int*)(ws + 27785056);      //         32
  int* csr_off   = (int*)(ws + 27785216);      //     80,008
  int* pairs     = (int*)(ws + 27865344);      //    720,064
  // contiguous zero region (ONE memset):
  const size_t Z = 28585472;
  int* cnt       = (int*)(ws + Z);             //     80,008
  int* dirtyA    = (int*)(ws + Z + 80008);     //     80,004
  int* dirty_n   = (int*)(ws + Z + 160012);    //     80,004
  int* ctrs      = (int*)(ws + Z + 240016);    //         64
  int* emask     = (int*)(ws + Z + 240080);    //    120,000
  int* emap      = (int*)(ws + Z + 360080);    //    480,000
  const size_t ZBYTES = 840080;
  if (ws_size < Z + ZBYTES) return;  // insufficient scratch; output stays poisoned

  hipMemsetAsync(ws + Z, 0, ZBYTES, stream);

  init_kernel<<<B_, 256, 0, stream>>>(r_idx, ents, arity, pos_table, query_emb,
                                      seednode, seedvec, dirtyA, dirty_n, meta);
  count_kernel<<<(E_ * A_ + 255) / 256, 256, 0, stream>>>(edge_list, cnt, emask);
  scan_kernel<<<1, SCAN_T, 0, stream>>>(cnt, csr_off);
  fill_kernel<<<(E_ * A_ + 255) / 256, 256, 0, stream>>>(edge_list, cnt, pairs);

  const float* rel0 = rel_emb;             // layer 0
  const float* rel1 = rel_emb + R_ * D_;   // layer 1

  mainL0_kernel<<<(N_ + 31) / 32, 256, 0, stream>>>(
      csr_off, pairs, rel_list, emask, pos_table, rel0, H1,
      W_agg, b_lin, ln_g, ln_b);
  eps_kernel<<<(E_ + 3) / 4, 256, 0, stream>>>(
      edge_list, rel_list, rel0, dirtyA, dirty_n, seednode, seedvec,
      Scorr, emap, ctrs);
  corr_kernel<<<(N_ + 3) / 4, 256, 0, stream>>>(
      csr_off, pairs, rel_list, emask, pos_table, rel0, Scorr, emap,
      dirty_n, seednode, seedvec, cmap, Hcorr,
      W_agg, W_self, b_lin, ln_g, ln_b, ctrs);
  cand_kernel<<<(B_ * C_ + 7) / 8, 512, 0, stream>>>(
      ents, meta, csr_off, pairs, edge_list, rel_list, pos_table, rel1,
      H1, Hcorr, cmap, dirty_n, query_emb,
      W_agg + D_ * D_, W_self + D_ * D_, b_lin + D_, ln_g + D_, ln_b + D_,
      W1, b1, W2, b2, out);

  (void)in_sizes; (void)n_in; (void)out_size;
}

// Round 8
// 146.721 us; speedup vs baseline: 2.4170x; 1.0047x over previous
//
#include <hip/hip_runtime.h>

#define D_ 64
#define L_ 2
#define R_ 50
#define N_ 20001
#define A_ 6
#define E_ 30000
#define B_ 4
#define C_ 500
#define FEAT_ 128
#define SC_CAP 8192

__device__ __forceinline__ float rlane(float v, int k) {
  return __builtin_bit_cast(float, __builtin_amdgcn_readlane(__builtin_bit_cast(int, v), k));
}
__device__ __forceinline__ float wave_sum(float v) {
#pragma unroll
  for (int off = 32; off; off >>= 1) v += __shfl_xor(v, off);
  return v;
}
// runtime-index select from 6 named regs (avoids scratch spill of reg arrays)
__device__ __forceinline__ float sel6(float p0, float p1, float p2, float p3,
                                      float p4, float p5, int a) {
  float r = p0;
  r = (a == 1) ? p1 : r; r = (a == 2) ? p2 : r; r = (a == 3) ? p3 : r;
  r = (a == 4) ? p4 : r; r = (a == 5) ? p5 : r;
  return r;
}

// ---------- fast zero of the scratch region (replaces pathological rocclr fill) ----------

#define ZQUADS 37507  // 600112 bytes / 16

__global__ void zero_kernel(float4* __restrict__ z) {
  int i = blockIdx.x * blockDim.x + threadIdx.x;
  if (i < ZQUADS) z[i] = make_float4(0.f, 0.f, 0.f, 0.f);
}

// ---------- init: pos_search + seed table + dirty marks ----------

__global__ void init_kernel(const int* __restrict__ r_idx, const int* __restrict__ ents,
                            const int* __restrict__ arity,
                            const float* __restrict__ pos_table,
                            const float* __restrict__ query_emb,
                            int* __restrict__ seednode, float* __restrict__ seedvec,
                            int* __restrict__ dirtyA, int* __restrict__ dirty_n,
                            int* __restrict__ meta) {
  int b = blockIdx.x, t = threadIdx.x;
  __shared__ int diff[A_];
  if (t < A_) diff[t] = 0;
  __syncthreads();
#pragma unroll
  for (int a = 0; a < A_; ++a) {
    int v0 = ents[(b * C_) * A_ + a];
    int dd = 0;
    for (int c = t; c < C_; c += 256) dd |= (ents[(b * C_ + c) * A_ + a] != v0);
    if (dd) diff[a] = 1;
  }
  __syncthreads();
  int ps = 0;
  for (int a = A_ - 1; a >= 0; --a) if (diff[a]) ps = a;
  int qr = r_idx[b * C_];
  if (t == 0) { meta[b] = ps; meta[B_ + b] = qr; }
  int ar = arity[b * C_];
  int lane = t & 63;
  for (int a = (t >> 6); a < A_; a += 4) {
    int slot = b * A_ + a;
    if (a < ar && a != ps) {
      int n = ents[(b * C_) * A_ + a];
      seedvec[slot * D_ + lane] = query_emb[qr * D_ + lane] + pos_table[(a + 1) * D_ + lane];
      if (lane == 0) {
        seednode[slot] = n;
        atomicOr(&dirtyA[n], 1 << b);
        atomicOr(&dirty_n[n], 1 << b);
      }
    } else {
      if (lane == 0) seednode[slot] = 0;
    }
  }
}

// ---------- CSR build (+ per-edge valid mask) ----------

__global__ void count_kernel(const int* __restrict__ edge_list, int* __restrict__ cnt,
                             int* __restrict__ emask) {
  int i = blockIdx.x * blockDim.x + threadIdx.x;
  if (i >= E_ * A_) return;
  int n = edge_list[i];
  if (n) {
    atomicAdd(&cnt[n], 1);
    atomicOr(&emask[i / A_], 1 << (i % A_));
  }
}

#define SCAN_T 1024
#define CHUNK 20
__global__ void scan_kernel(int* __restrict__ cnt, int* __restrict__ off) {
  __shared__ int part[SCAN_T];
  int t = threadIdx.x;
  int base = t * CHUNK;
  int v[CHUNK];
  int s = 0;
#pragma unroll
  for (int i = 0; i < CHUNK; ++i) {
    int idx = base + i;
    v[i] = (idx < N_) ? cnt[idx] : 0;
    s += v[i];
  }
  part[t] = s;
  __syncthreads();
  for (int d = 1; d < SCAN_T; d <<= 1) {
    int x = part[t];
    int y = (t >= d) ? part[t - d] : 0;
    __syncthreads();
    part[t] = x + y;
    __syncthreads();
  }
  int run = (t == 0) ? 0 : part[t - 1];
#pragma unroll
  for (int i = 0; i < CHUNK; ++i) {
    int idx = base + i;
    if (idx < N_) {
      off[idx] = run;
      cnt[idx] = run;  // cursor for fill
      run += v[i];
    }
  }
  if (t == SCAN_T - 1) off[N_] = part[SCAN_T - 1];
}

__global__ void fill_kernel(const int* __restrict__ edge_list, int* __restrict__ cur,
                            int* __restrict__ pairs) {
  int i = blockIdx.x * blockDim.x + threadIdx.x;
  if (i >= E_ * A_) return;
  int n = edge_list[i];
  if (n) {
    int p = atomicAdd(&cur[n], 1);
    pairs[p] = i;
  }
}

// ---------- layer-0 batch-collapsed node update -> H1[n][64] ----------
// agg[n] = sum_pairs rel_e ⊙ (possum_e - pos_a);  H1 = relu(LN(agg@Wa + b_lin))

__global__ __launch_bounds__(256) void mainL0_kernel(
    const int* __restrict__ csr_off, const int* __restrict__ pairs,
    const int* __restrict__ rel_list, const int* __restrict__ emask,
    const float* __restrict__ pos_table, const float* __restrict__ rel_emb_l,
    float* __restrict__ H1,
    const float* __restrict__ Wa, const float* __restrict__ bl_,
    const float* __restrict__ g_, const float* __restrict__ be_) {
  __shared__ float A_lds[32 * 68];
  __shared__ float B_lds[64 * 64];
  int t = threadIdx.x;
  int m0 = blockIdx.x * 32;
  int ty = t >> 4, tx = t & 15;
  int wv = t >> 6, l = t & 63;

  float pv0 = pos_table[1 * D_ + l], pv1 = pos_table[2 * D_ + l];
  float pv2 = pos_table[3 * D_ + l], pv3 = pos_table[4 * D_ + l];
  float pv4 = pos_table[5 * D_ + l], pv5 = pos_table[6 * D_ + l];

#pragma unroll
  for (int it = 0; it < 4; ++it) {
    int idx = t + 256 * it;
    reinterpret_cast<float4*>(B_lds)[idx] = reinterpret_cast<const float4*>(Wa)[idx];
  }

  for (int q = 0; q < 8; ++q) {
    int li = wv * 8 + q;
    int n = m0 + li;
    float aggv = 0.f;
    if (n < N_) {
      int p0 = __builtin_amdgcn_readfirstlane(csr_off[n]);
      int p1 = __builtin_amdgcn_readfirstlane(csr_off[n + 1]);
      for (int p = p0; p < p1; p += 8) {
        int cnt = p1 - p;
        int idx8[8];
#pragma unroll
        for (int u = 0; u < 8; ++u) idx8[u] = (u < cnt) ? pairs[p + u] : -1;
#pragma unroll
        for (int u = 0; u < 8; ++u) {
          if (idx8[u] >= 0) {
            int e = idx8[u] / 6, a = idx8[u] - e * 6;
            int msk = emask[e];
            float rel = rel_emb_l[rel_list[e] * D_ + l];
            float possum = 0.f;
            possum += (msk & 1) ? pv0 : 0.f;
            possum += (msk & 2) ? pv1 : 0.f;
            possum += (msk & 4) ? pv2 : 0.f;
            possum += (msk & 8) ? pv3 : 0.f;
            possum += (msk & 16) ? pv4 : 0.f;
            possum += (msk & 32) ? pv5 : 0.f;
            float pa = sel6(pv0, pv1, pv2, pv3, pv4, pv5, a);
            aggv = fmaf(rel, possum - pa, aggv);
          }
        }
      }
    }
    A_lds[li * 68 + l] = aggv;
  }
  __syncthreads();

  float acc[2][4];
  float4 bl4 = *reinterpret_cast<const float4*>(&bl_[tx * 4]);
#pragma unroll
  for (int i = 0; i < 2; ++i) {
    acc[i][0] = bl4.x; acc[i][1] = bl4.y; acc[i][2] = bl4.z; acc[i][3] = bl4.w;
  }
#pragma unroll 8
  for (int k = 0; k < 64; ++k) {
    float4 b4 = *reinterpret_cast<const float4*>(&B_lds[k * 64 + tx * 4]);
    float a0 = A_lds[(ty * 2 + 0) * 68 + k];
    float a1 = A_lds[(ty * 2 + 1) * 68 + k];
    acc[0][0] = fmaf(a0, b4.x, acc[0][0]); acc[0][1] = fmaf(a0, b4.y, acc[0][1]);
    acc[0][2] = fmaf(a0, b4.z, acc[0][2]); acc[0][3] = fmaf(a0, b4.w, acc[0][3]);
    acc[1][0] = fmaf(a1, b4.x, acc[1][0]); acc[1][1] = fmaf(a1, b4.y, acc[1][1]);
    acc[1][2] = fmaf(a1, b4.z, acc[1][2]); acc[1][3] = fmaf(a1, b4.w, acc[1][3]);
  }
  __syncthreads();
#pragma unroll
  for (int i = 0; i < 2; ++i) {
    float4 v = make_float4(acc[i][0], acc[i][1], acc[i][2], acc[i][3]);
    *reinterpret_cast<float4*>(&A_lds[(ty * 2 + i) * 68 + tx * 4]) = v;
  }
  __syncthreads();

  float g = g_[l], be = be_[l];
#pragma unroll 4
  for (int rr = 0; rr < 8; ++rr) {
    int r = wv * 8 + rr;
    int n = m0 + r;
    float x = A_lds[r * 68 + l];
    float mu = wave_sum(x) * (1.f / 64.f);
    float dx = x - mu;
    float var = wave_sum(dx * dx) * (1.f / 64.f);
    float y = dx * rsqrtf(var + 1e-5f) * g + be;
    if (n < N_) H1[n * D_ + l] = fmaxf(y, 0.f);
  }
}

// ---------- fused edge-prop + Scorr (wave per edge) ----------

__global__ __launch_bounds__(256) void eps_kernel(
    const int* __restrict__ edge_list, const int* __restrict__ rel_list,
    const float* __restrict__ rel_emb_l,
    const int* __restrict__ dirtyA, int* __restrict__ dirty_n,
    const int* __restrict__ seednode, const float* __restrict__ seedvec,
    float* __restrict__ Scorr, unsigned short* __restrict__ emap,
    int* __restrict__ ctrs) {
  int e = blockIdx.x * 4 + (threadIdx.x >> 6);
  int lane = threadIdx.x & 63;
  if (e >= E_) return;
  int mem[A_];
  int m = 0;
#pragma unroll
  for (int a = 0; a < A_; ++a) {
    mem[a] = edge_list[e * A_ + a];
    if (mem[a]) m |= dirtyA[mem[a]];
  }
  if (!m) return;
#pragma unroll
  for (int a = 0; a < A_; ++a)
    if (lane == a && mem[a]) atomicOr(&dirty_n[mem[a]], m);
  float rel = rel_emb_l[rel_list[e] * D_ + lane];
#pragma unroll
  for (int b = 0; b < B_; ++b) {
    if ((m >> b) & 1) {
      float s = 0.f;
#pragma unroll
      for (int a = 0; a < A_; ++a) {
        if (mem[a]) {
#pragma unroll
          for (int j = 0; j < A_; ++j) {
            int sl = b * A_ + j;
            if (seednode[sl] == mem[a]) s += seedvec[sl * D_ + lane];
          }
        }
      }
      int slot = 0;
      if (lane == 0) slot = atomicAdd(&ctrs[1], 1);
      slot = __shfl(slot, 0);
      if (slot < SC_CAP) {
        Scorr[slot * D_ + lane] = rel * s;
        if (lane == 0) emap[e * B_ + b] = (unsigned short)(slot + 1);
      }
    }
  }
}

// ---------- exact recompute of dirty layer-1 rows -> Hcorr (+cmap), self-compacting ----------

__global__ __launch_bounds__(256) void corr_kernel(
    const int* __restrict__ csr_off, const int* __restrict__ pairs,
    const int* __restrict__ rel_list, const int* __restrict__ emask,
    const float* __restrict__ pos_table, const float* __restrict__ rel_emb_l,
    const float* __restrict__ Scorr, const unsigned short* __restrict__ emap,
    const int* __restrict__ dirty_n,
    const int* __restrict__ seednode, const float* __restrict__ seedvec,
    int* __restrict__ cmap, float* __restrict__ Hcorr,
    const float* __restrict__ Wa, const float* __restrict__ Ws,
    const float* __restrict__ bl_, const float* __restrict__ g_,
    const float* __restrict__ be_, int* __restrict__ ctrs) {
  __shared__ float WaL[64 * 64];
  __shared__ float WsL[64 * 64];
  int t = threadIdx.x;
  int wv = t >> 6, lane = t & 63;
  int n = blockIdx.x * 4 + wv;
  int m = (n < N_) ? dirty_n[n] : 0;
  if (__syncthreads_or(m) == 0) return;  // whole block clean
#pragma unroll
  for (int it = 0; it < 4; ++it) {
    int idx = t + 256 * it;
    reinterpret_cast<float4*>(WaL)[idx] = reinterpret_cast<const float4*>(Wa)[idx];
    reinterpret_cast<float4*>(WsL)[idx] = reinterpret_cast<const float4*>(Ws)[idx];
  }
  __syncthreads();
  if (!m) return;

  float pv0 = pos_table[1 * D_ + lane], pv1 = pos_table[2 * D_ + lane];
  float pv2 = pos_table[3 * D_ + lane], pv3 = pos_table[4 * D_ + lane];
  float pv4 = pos_table[5 * D_ + lane], pv5 = pos_table[6 * D_ + lane];

  int slot = 0;
  if (lane == 0) slot = atomicAdd(&ctrs[2], 1);
  slot = __shfl(slot, 0);
  if (lane == 0) cmap[n] = slot;

  float blv = bl_[lane], gv = g_[lane], bev = be_[lane];
  int p0 = csr_off[n], p1 = csr_off[n + 1];
  float ss0 = 0.f, ss1 = 0.f, ss2 = 0.f, ss3 = 0.f;
  float rs = 0.f, ps = 0.f;
  for (int p = p0; p < p1; ++p) {
    int ii = pairs[p];
    int e = ii / 6, a = ii - e * 6;
    int msk = emask[e];
    float rel = rel_emb_l[rel_list[e] * D_ + lane];
    float possum = 0.f;
    possum += (msk & 1) ? pv0 : 0.f;
    possum += (msk & 2) ? pv1 : 0.f;
    possum += (msk & 4) ? pv2 : 0.f;
    possum += (msk & 8) ? pv3 : 0.f;
    possum += (msk & 16) ? pv4 : 0.f;
    possum += (msk & 32) ? pv5 : 0.f;
    float base = rel * possum;
    rs += rel;
    ps = fmaf(rel, sel6(pv0, pv1, pv2, pv3, pv4, pv5, a), ps);
    if ((m >> 0) & 1) { int ei = emap[e * B_ + 0]; ss0 += base + (ei ? Scorr[(ei - 1) * D_ + lane] : 0.f); }
    if ((m >> 1) & 1) { int ei = emap[e * B_ + 1]; ss1 += base + (ei ? Scorr[(ei - 1) * D_ + lane] : 0.f); }
    if ((m >> 2) & 1) { int ei = emap[e * B_ + 2]; ss2 += base + (ei ? Scorr[(ei - 1) * D_ + lane] : 0.f); }
    if ((m >> 3) & 1) { int ei = emap[e * B_ + 3]; ss3 += base + (ei ? Scorr[(ei - 1) * D_ + lane] : 0.f); }
  }
#pragma unroll
  for (int b = 0; b < B_; ++b) {
    if ((m >> b) & 1) {
      float ssb = (b == 0) ? ss0 : (b == 1) ? ss1 : (b == 2) ? ss2 : ss3;
      float hv = 0.f;
#pragma unroll
      for (int j = 0; j < A_; ++j) {
        int sl = b * A_ + j;
        if (seednode[sl] == n) hv += seedvec[sl * D_ + lane];
      }
      float aggv = ssb - hv * rs - ps;
      float out = blv;
#pragma unroll 16
      for (int k = 0; k < 64; ++k) {
        out = fmaf(rlane(aggv, k), WaL[k * 64 + lane], out);
        out = fmaf(rlane(hv, k), WsL[k * 64 + lane], out);
      }
      float mu = wave_sum(out) * (1.f / 64.f);
      float dx = out - mu;
      float var = wave_sum(dx * dx) * (1.f / 64.f);
      float y = dx * rsqrtf(var + 1e-5f) * gv + bev;
      Hcorr[(slot * B_ + b) * D_ + lane] = fmaxf(y, 0.f) + hv;
    }
  }
}

// ---------- layer-2 at candidates only, fused with scoring MLP (h1 via overlay) ----------

__global__ __launch_bounds__(512) void cand_kernel(
    const int* __restrict__ ents, const int* __restrict__ meta,
    const int* __restrict__ csr_off, const int* __restrict__ pairs,
    const int* __restrict__ edge_list, const int* __restrict__ rel_list,
    const float* __restrict__ pos_table, const float* __restrict__ rel_emb_l,
    const float* __restrict__ H1, const float* __restrict__ Hcorr,
    const int* __restrict__ cmap, const int* __restrict__ dirty_n,
    const float* __restrict__ query_emb,
    const float* __restrict__ Wa, const float* __restrict__ Ws,
    const float* __restrict__ bl_, const float* __restrict__ g_,
    const float* __restrict__ be_,
    const float* __restrict__ W1, const float* __restrict__ b1,
    const float* __restrict__ W2, const float* __restrict__ b2,
    float* __restrict__ out) {
  __shared__ float WaL[64 * 64];
  __shared__ float WsL[64 * 64];
  int t = threadIdx.x;
#pragma unroll
  for (int it = 0; it < 2; ++it) {
    int idx = t + 512 * it;
    reinterpret_cast<float4*>(WaL)[idx] = reinterpret_cast<const float4*>(Wa)[idx];
    reinterpret_cast<float4*>(WsL)[idx] = reinterpret_cast<const float4*>(Ws)[idx];
  }
  __syncthreads();
  int w = blockIdx.x * 8 + (t >> 6);
  int lane = t & 63;
  if (w >= B_ * C_) return;
  int b = w / C_;
  int c = w - b * C_;
  int psn = meta[b];
  int qr = meta[B_ + b];
  int n = ents[(b * C_ + c) * A_ + psn];

  float pv0 = pos_table[1 * D_ + lane], pv1 = pos_table[2 * D_ + lane];
  float pv2 = pos_table[3 * D_ + lane], pv3 = pos_table[4 * D_ + lane];
  float pv4 = pos_table[5 * D_ + lane], pv5 = pos_table[6 * D_ + lane];

  float h1v = H1[n * D_ + lane];
  if ((dirty_n[n] >> b) & 1) h1v = Hcorr[(cmap[n] * B_ + b) * D_ + lane];

  int p0 = __builtin_amdgcn_readfirstlane(csr_off[n]);
  int p1 = __builtin_amdgcn_readfirstlane(csr_off[n + 1]);
  float aggv = 0.f;
  for (int p = p0; p < p1; ++p) {
    int ii = pairs[p];
    int e = ii / 6, a = ii - e * 6;
    float rel = rel_emb_l[rel_list[e] * D_ + lane];
    float s = 0.f;
#pragma unroll
    for (int a2 = 0; a2 < A_; ++a2) {
      int m2 = edge_list[e * A_ + a2];
      if (m2) {
        float hm = H1[m2 * D_ + lane];
        if ((dirty_n[m2] >> b) & 1) hm = Hcorr[(cmap[m2] * B_ + b) * D_ + lane];
        float pa2 = sel6(pv0, pv1, pv2, pv3, pv4, pv5, a2);
        s += hm + pa2;
      }
    }
    float pa = sel6(pv0, pv1, pv2, pv3, pv4, pv5, a);
    aggv = fmaf(s - h1v - pa, rel, aggv);
  }

  float outv = bl_[lane];
#pragma unroll 16
  for (int k = 0; k < 64; ++k) {
    outv = fmaf(rlane(aggv, k), WaL[k * 64 + lane], outv);
    outv = fmaf(rlane(h1v, k), WsL[k * 64 + lane], outv);
  }
  float mu = wave_sum(outv) * (1.f / 64.f);
  float dx = outv - mu;
  float var = wave_sum(dx * dx) * (1.f / 64.f);
  float y = dx * rsqrtf(var + 1e-5f) * g_[lane] + be_[lane];
  float h2v = fmaxf(y, 0.f) + h1v;

  float qv = query_emb[qr * D_ + lane];
  float hid0 = b1[lane];
  float hid1 = b1[D_ + lane];
#pragma unroll
  for (int k = 0; k < D_; ++k) {
    float f = rlane(h2v, k);
    hid0 = fmaf(f, W1[k * FEAT_ + lane], hid0);
    hid1 = fmaf(f, W1[k * FEAT_ + D_ + lane], hid1);
  }
#pragma unroll
  for (int k = 0; k < D_; ++k) {
    float q = rlane(qv, k);
    hid0 = fmaf(q, W1[(D_ + k) * FEAT_ + lane], hid0);
    hid1 = fmaf(q, W1[(D_ + k) * FEAT_ + D_ + lane], hid1);
  }
  float accs = fmaxf(hid0, 0.f) * W2[lane] + fmaxf(hid1, 0.f) * W2[D_ + lane];
  accs = wave_sum(accs);
  if (lane == 0) out[w] = accs + b2[0];
}

// ---------- launch ----------

extern "C" void kernel_launch(void* const* d_in, const int* in_sizes, int n_in,
                              void* d_out, int out_size, void* d_ws, size_t ws_size,
                              hipStream_t stream) {
  const int* r_idx = (const int*)d_in[0];
  const int* ents = (const int*)d_in[1];
  const int* arity = (const int*)d_in[2];
  const int* edge_list = (const int*)d_in[3];
  const int* rel_list = (const int*)d_in[4];
  const float* pos_table = (const float*)d_in[5];
  const float* query_emb = (const float*)d_in[6];
  const float* rel_emb = (const float*)d_in[7];
  const float* W_agg = (const float*)d_in[8];
  const float* W_self = (const float*)d_in[9];
  const float* b_lin = (const float*)d_in[10];
  const float* ln_g = (const float*)d_in[11];
  const float* ln_b = (const float*)d_in[12];
  const float* W1 = (const float*)d_in[13];
  const float* b1 = (const float*)d_in[14];
  const float* W2 = (const float*)d_in[15];
  const float* b2 = (const float*)d_in[16];
  float* out = (float*)d_out;

  char* ws = (char*)d_ws;
  // layout (bytes)
  float* H1      = (float*)(ws + 0);           //  5,120,256
  float* Hcorr   = (float*)(ws + 5120512);     // 20,481,024 (full-capacity overlay)
  float* Scorr   = (float*)(ws + 25601536);    //  2,097,152
  int* cmap      = (int*)(ws + 27698688);      //     80,004
  int* seednode  = (int*)(ws + 27778816);      //         96
  float* seedvec = (float*)(ws + 27778912);    //      6,144
  int* meta      = (int*)(ws + 27785056);      //         32
  int* csr_off   = (int*)(ws + 27785216);      //     80,008
  int* pairs     = (int*)(ws + 27865344);      //    720,064
  // contiguous zero region (cleared by zero_kernel):
  const size_t Z = 28585472;  // 16-aligned
  int* cnt       = (int*)(ws + Z);                       //  80,016 (padded)
  int* dirtyA    = (int*)(ws + Z + 80016);               //  80,016
  int* dirty_n   = (int*)(ws + Z + 160032);              //  80,016
  int* ctrs      = (int*)(ws + Z + 240048);              //      64
  int* emask     = (int*)(ws + Z + 240112);              // 120,000
  unsigned short* emap = (unsigned short*)(ws + Z + 360112);  // 240,000
  const size_t ZBYTES = 600112;  // = ZQUADS*16
  if (ws_size < Z + ZBYTES) return;  // insufficient scratch; output stays poisoned

  zero_kernel<<<(ZQUADS + 255) / 256, 256, 0, stream>>>((float4*)(ws + Z));

  init_kernel<<<B_, 256, 0, stream>>>(r_idx, ents, arity, pos_table, query_emb,
                                      seednode, seedvec, dirtyA, dirty_n, meta);
  count_kernel<<<(E_ * A_ + 255) / 256, 256, 0, stream>>>(edge_list, cnt, emask);
  scan_kernel<<<1, SCAN_T, 0, stream>>>(cnt, csr_off);
  fill_kernel<<<(E_ * A_ + 255) / 256, 256, 0, stream>>>(edge_list, cnt, pairs);

  const float* rel0 = rel_emb;             // layer 0
  const float* rel1 = rel_emb + R_ * D_;   // layer 1

  mainL0_kernel<<<(N_ + 31) / 32, 256, 0, stream>>>(
      csr_off, pairs, rel_list, emask, pos_table, rel0, H1,
      W_agg, b_lin, ln_g, ln_b);
  eps_kernel<<<(E_ + 3) / 4, 256, 0, stream>>>(
      edge_list, rel_list, rel0, dirtyA, dirty_n, seednode, seedvec,
      Scorr, emap, ctrs);
  corr_kernel<<<(N_ + 3) / 4, 256, 0, stream>>>(
      csr_off, pairs, rel_list, emask, pos_table, rel0, Scorr, emap,
      dirty_n, seednode, seedvec, cmap, Hcorr,
      W_agg, W_self, b_lin, ln_g, ln_b, ctrs);
  cand_kernel<<<(B_ * C_ + 7) / 8, 512, 0, stream>>>(
      ents, meta, csr_off, pairs, edge_list, rel_list, pos_table, rel1,
      H1, Hcorr, cmap, dirty_n, query_emb,
      W_agg + D_ * D_, W_self + D_ * D_, b_lin + D_, ln_g + D_, ln_b + D_,
      W1, b1, W2, b2, out);

  (void)in_sizes; (void)n_in; (void)out_size;
}

// Round 9
// 113.225 us; speedup vs baseline: 3.1320x; 1.2958x over previous
//
#include <hip/hip_runtime.h>

#define D_ 64
#define L_ 2
#define R_ 50
#define N_ 20001
#define A_ 6
#define E_ 30000
#define B_ 4
#define C_ 500
#define FEAT_ 128
#define SC_CAP 8192
#define DCAP 64  // bucket capacity per node (deg ~Poisson(6); P(>=64) ~ 1e-40)

__device__ __forceinline__ float rlane(float v, int k) {
  return __builtin_bit_cast(float, __builtin_amdgcn_readlane(__builtin_bit_cast(int, v), k));
}
__device__ __forceinline__ float wave_sum(float v) {
#pragma unroll
  for (int off = 32; off; off >>= 1) v += __shfl_xor(v, off);
  return v;
}
// runtime-index select from 6 named regs (avoids scratch spill of reg arrays)
__device__ __forceinline__ float sel6(float p0, float p1, float p2, float p3,
                                      float p4, float p5, int a) {
  float r = p0;
  r = (a == 1) ? p1 : r; r = (a == 2) ? p2 : r; r = (a == 3) ? p3 : r;
  r = (a == 4) ? p4 : r; r = (a == 5) ? p5 : r;
  return r;
}

// ---------- K1: zero scratch (deg + dirtyA + dirty_n + ctrs) ----------

#define ZQUADS 15007  // 240112 / 16

__global__ void zero_kernel(float4* __restrict__ z) {
  int i = blockIdx.x * blockDim.x + threadIdx.x;
  if (i < ZQUADS) z[i] = make_float4(0.f, 0.f, 0.f, 0.f);
}

// ---------- K2: init (4 blocks) ∪ emask build (118) ∪ bucket build (704) ----------

#define IB_INIT 4
#define IB_EMASK ((E_ + 255) / 256)            // 118
#define IB_BUCKET ((E_ * A_ + 255) / 256)      // 704
#define IB_BLOCKS (IB_INIT + IB_EMASK + IB_BUCKET)

__global__ __launch_bounds__(256) void init_bucket_kernel(
    const int* __restrict__ r_idx, const int* __restrict__ ents,
    const int* __restrict__ arity, const float* __restrict__ pos_table,
    const float* __restrict__ query_emb, const int* __restrict__ edge_list,
    int* __restrict__ seednode, float* __restrict__ seedvec,
    int* __restrict__ dirtyA, int* __restrict__ dirty_n, int* __restrict__ meta,
    int* __restrict__ deg, int* __restrict__ bucket, int* __restrict__ emask) {
  __shared__ int diff[A_];
  int bid = blockIdx.x, t = threadIdx.x;
  if (bid < IB_INIT) {
    int b = bid;
    if (t < A_) diff[t] = 0;
    __syncthreads();
#pragma unroll
    for (int a = 0; a < A_; ++a) {
      int v0 = ents[(b * C_) * A_ + a];
      int dd = 0;
      for (int c = t; c < C_; c += 256) dd |= (ents[(b * C_ + c) * A_ + a] != v0);
      if (dd) diff[a] = 1;
    }
    __syncthreads();
    int ps = 0;
    for (int a = A_ - 1; a >= 0; --a) if (diff[a]) ps = a;
    int qr = r_idx[b * C_];
    if (t == 0) { meta[b] = ps; meta[B_ + b] = qr; }
    int ar = arity[b * C_];
    int lane = t & 63;
    for (int a = (t >> 6); a < A_; a += 4) {
      int slot = b * A_ + a;
      if (a < ar && a != ps) {
        int n = ents[(b * C_) * A_ + a];
        seedvec[slot * D_ + lane] = query_emb[qr * D_ + lane] + pos_table[(a + 1) * D_ + lane];
        if (lane == 0) {
          seednode[slot] = n;
          atomicOr(&dirtyA[n], 1 << b);
          atomicOr(&dirty_n[n], 1 << b);
        }
      } else {
        if (lane == 0) seednode[slot] = 0;
      }
    }
  } else if (bid < IB_INIT + IB_EMASK) {
    int e = (bid - IB_INIT) * 256 + t;
    if (e < E_) {
      int msk = 0;
#pragma unroll
      for (int a = 0; a < A_; ++a)
        if (edge_list[e * A_ + a]) msk |= 1 << a;
      emask[e] = msk;
    }
  } else {
    int i = (bid - IB_INIT - IB_EMASK) * 256 + t;
    if (i < E_ * A_) {
      int n = edge_list[i];
      if (n) {
        int slot = atomicAdd(&deg[n], 1);
        if (slot < DCAP) bucket[n * DCAP + slot] = i;
      }
    }
  }
}

// ---------- K3: mainL0 (626 blocks) ∪ eps (7500 blocks) ----------
// mainL0: agg[n] = sum_pairs rel_e ⊙ (possum_e - pos_a); H1 = relu(LN(agg@Wa + b_lin))
// eps:    dirty-prop + Scorr[(e,b)] = rel_e ⊙ Σ_members δ0 (seed table); emap fully written

#define MAIN_BLOCKS ((N_ + 31) / 32)   // 626
#define EPS_BLOCKS ((E_ + 3) / 4)      // 7500

__global__ __launch_bounds__(256) void main_eps_kernel(
    const int* __restrict__ deg, const int* __restrict__ bucket,
    const int* __restrict__ edge_list, const int* __restrict__ rel_list,
    const int* __restrict__ emask,
    const float* __restrict__ pos_table, const float* __restrict__ rel_emb_l,
    float* __restrict__ H1,
    const float* __restrict__ Wa, const float* __restrict__ bl_,
    const float* __restrict__ g_, const float* __restrict__ be_,
    const int* __restrict__ dirtyA, int* __restrict__ dirty_n,
    const int* __restrict__ seednode, const float* __restrict__ seedvec,
    float* __restrict__ Scorr, unsigned short* __restrict__ emap,
    int* __restrict__ ctrs) {
  __shared__ float A_lds[32 * 68];
  __shared__ float B_lds[64 * 64];
  int t = threadIdx.x;
  int wv = t >> 6, l = t & 63;

  if (blockIdx.x >= MAIN_BLOCKS) {
    // ----- eps -----
    int e = (blockIdx.x - MAIN_BLOCKS) * 4 + wv;
    if (e >= E_) return;
    int mem[A_];
    int m = 0;
#pragma unroll
    for (int a = 0; a < A_; ++a) {
      mem[a] = edge_list[e * A_ + a];
      if (mem[a]) m |= dirtyA[mem[a]];
    }
    if (!m) {
      if (l == 0) *reinterpret_cast<unsigned long long*>(&emap[e * B_]) = 0ull;
      return;
    }
    if (l == 0) *reinterpret_cast<unsigned long long*>(&emap[e * B_]) = 0ull;
#pragma unroll
    for (int a = 0; a < A_; ++a)
      if (l == a && mem[a]) atomicOr(&dirty_n[mem[a]], m);
    float rel = rel_emb_l[rel_list[e] * D_ + l];
#pragma unroll
    for (int b = 0; b < B_; ++b) {
      if ((m >> b) & 1) {
        float s = 0.f;
#pragma unroll
        for (int a = 0; a < A_; ++a) {
          if (mem[a]) {
#pragma unroll
            for (int j = 0; j < A_; ++j) {
              int sl = b * A_ + j;
              if (seednode[sl] == mem[a]) s += seedvec[sl * D_ + l];
            }
          }
        }
        int slot = 0;
        if (l == 0) slot = atomicAdd(&ctrs[1], 1);
        slot = __shfl(slot, 0);
        if (slot < SC_CAP) {
          Scorr[slot * D_ + l] = rel * s;
          if (l == 0) emap[e * B_ + b] = (unsigned short)(slot + 1);
        }
      }
    }
    return;
  }

  // ----- mainL0 -----
  int m0 = blockIdx.x * 32;
  int ty = t >> 4, tx = t & 15;

  float pv0 = pos_table[1 * D_ + l], pv1 = pos_table[2 * D_ + l];
  float pv2 = pos_table[3 * D_ + l], pv3 = pos_table[4 * D_ + l];
  float pv4 = pos_table[5 * D_ + l], pv5 = pos_table[6 * D_ + l];

#pragma unroll
  for (int it = 0; it < 4; ++it) {
    int idx = t + 256 * it;
    reinterpret_cast<float4*>(B_lds)[idx] = reinterpret_cast<const float4*>(Wa)[idx];
  }

  for (int q = 0; q < 8; ++q) {
    int li = wv * 8 + q;
    int n = m0 + li;
    float aggv = 0.f;
    if (n < N_) {
      int dg = __builtin_amdgcn_readfirstlane(deg[n]);
      int base = n * DCAP;
      for (int p = 0; p < dg; p += 8) {
        int cnt = dg - p;
        int idx8[8];
#pragma unroll
        for (int u = 0; u < 8; ++u) idx8[u] = (u < cnt) ? bucket[base + p + u] : -1;
#pragma unroll
        for (int u = 0; u < 8; ++u) {
          if (idx8[u] >= 0) {
            int e = idx8[u] / 6, a = idx8[u] - e * 6;
            int msk = emask[e];
            float rel = rel_emb_l[rel_list[e] * D_ + l];
            float possum = 0.f;
            possum += (msk & 1) ? pv0 : 0.f;
            possum += (msk & 2) ? pv1 : 0.f;
            possum += (msk & 4) ? pv2 : 0.f;
            possum += (msk & 8) ? pv3 : 0.f;
            possum += (msk & 16) ? pv4 : 0.f;
            possum += (msk & 32) ? pv5 : 0.f;
            float pa = sel6(pv0, pv1, pv2, pv3, pv4, pv5, a);
            aggv = fmaf(rel, possum - pa, aggv);
          }
        }
      }
    }
    A_lds[li * 68 + l] = aggv;
  }
  __syncthreads();

  float acc[2][4];
  float4 bl4 = *reinterpret_cast<const float4*>(&bl_[tx * 4]);
#pragma unroll
  for (int i = 0; i < 2; ++i) {
    acc[i][0] = bl4.x; acc[i][1] = bl4.y; acc[i][2] = bl4.z; acc[i][3] = bl4.w;
  }
#pragma unroll 8
  for (int k = 0; k < 64; ++k) {
    float4 b4 = *reinterpret_cast<const float4*>(&B_lds[k * 64 + tx * 4]);
    float a0 = A_lds[(ty * 2 + 0) * 68 + k];
    float a1 = A_lds[(ty * 2 + 1) * 68 + k];
    acc[0][0] = fmaf(a0, b4.x, acc[0][0]); acc[0][1] = fmaf(a0, b4.y, acc[0][1]);
    acc[0][2] = fmaf(a0, b4.z, acc[0][2]); acc[0][3] = fmaf(a0, b4.w, acc[0][3]);
    acc[1][0] = fmaf(a1, b4.x, acc[1][0]); acc[1][1] = fmaf(a1, b4.y, acc[1][1]);
    acc[1][2] = fmaf(a1, b4.z, acc[1][2]); acc[1][3] = fmaf(a1, b4.w, acc[1][3]);
  }
  __syncthreads();
#pragma unroll
  for (int i = 0; i < 2; ++i) {
    float4 v = make_float4(acc[i][0], acc[i][1], acc[i][2], acc[i][3]);
    *reinterpret_cast<float4*>(&A_lds[(ty * 2 + i) * 68 + tx * 4]) = v;
  }
  __syncthreads();

  float g = g_[l], be = be_[l];
#pragma unroll 4
  for (int rr = 0; rr < 8; ++rr) {
    int r = wv * 8 + rr;
    int n = m0 + r;
    float x = A_lds[r * 68 + l];
    float mu = wave_sum(x) * (1.f / 64.f);
    float dx = x - mu;
    float var = wave_sum(dx * dx) * (1.f / 64.f);
    float y = dx * rsqrtf(var + 1e-5f) * g + be;
    if (n < N_) H1[n * D_ + l] = fmaxf(y, 0.f);
  }
}

// ---------- K4: exact recompute of dirty layer-1 rows -> Hcorr (+cmap) ----------

__global__ __launch_bounds__(256) void corr_kernel(
    const int* __restrict__ deg, const int* __restrict__ bucket,
    const int* __restrict__ rel_list, const int* __restrict__ emask,
    const float* __restrict__ pos_table, const float* __restrict__ rel_emb_l,
    const float* __restrict__ Scorr, const unsigned short* __restrict__ emap,
    const int* __restrict__ dirty_n,
    const int* __restrict__ seednode, const float* __restrict__ seedvec,
    int* __restrict__ cmap, float* __restrict__ Hcorr,
    const float* __restrict__ Wa, const float* __restrict__ Ws,
    const float* __restrict__ bl_, const float* __restrict__ g_,
    const float* __restrict__ be_, int* __restrict__ ctrs) {
  __shared__ float WaL[64 * 64];
  __shared__ float WsL[64 * 64];
  int t = threadIdx.x;
  int wv = t >> 6, lane = t & 63;
  int n = blockIdx.x * 4 + wv;
  int m = (n < N_) ? dirty_n[n] : 0;
  if (__syncthreads_or(m) == 0) return;  // whole block clean
#pragma unroll
  for (int it = 0; it < 4; ++it) {
    int idx = t + 256 * it;
    reinterpret_cast<float4*>(WaL)[idx] = reinterpret_cast<const float4*>(Wa)[idx];
    reinterpret_cast<float4*>(WsL)[idx] = reinterpret_cast<const float4*>(Ws)[idx];
  }
  __syncthreads();
  if (!m) return;

  float pv0 = pos_table[1 * D_ + lane], pv1 = pos_table[2 * D_ + lane];
  float pv2 = pos_table[3 * D_ + lane], pv3 = pos_table[4 * D_ + lane];
  float pv4 = pos_table[5 * D_ + lane], pv5 = pos_table[6 * D_ + lane];

  int slot = 0;
  if (lane == 0) slot = atomicAdd(&ctrs[2], 1);
  slot = __shfl(slot, 0);
  if (lane == 0) cmap[n] = slot;

  float blv = bl_[lane], gv = g_[lane], bev = be_[lane];
  int dg = deg[n];
  int base = n * DCAP;
  float ss0 = 0.f, ss1 = 0.f, ss2 = 0.f, ss3 = 0.f;
  float rs = 0.f, ps = 0.f;
  for (int p = 0; p < dg; ++p) {
    int ii = bucket[base + p];
    int e = ii / 6, a = ii - e * 6;
    int msk = emask[e];
    float rel = rel_emb_l[rel_list[e] * D_ + lane];
    float possum = 0.f;
    possum += (msk & 1) ? pv0 : 0.f;
    possum += (msk & 2) ? pv1 : 0.f;
    possum += (msk & 4) ? pv2 : 0.f;
    possum += (msk & 8) ? pv3 : 0.f;
    possum += (msk & 16) ? pv4 : 0.f;
    possum += (msk & 32) ? pv5 : 0.f;
    float base_v = rel * possum;
    rs += rel;
    ps = fmaf(rel, sel6(pv0, pv1, pv2, pv3, pv4, pv5, a), ps);
    if ((m >> 0) & 1) { int ei = emap[e * B_ + 0]; ss0 += base_v + (ei ? Scorr[(ei - 1) * D_ + lane] : 0.f); }
    if ((m >> 1) & 1) { int ei = emap[e * B_ + 1]; ss1 += base_v + (ei ? Scorr[(ei - 1) * D_ + lane] : 0.f); }
    if ((m >> 2) & 1) { int ei = emap[e * B_ + 2]; ss2 += base_v + (ei ? Scorr[(ei - 1) * D_ + lane] : 0.f); }
    if ((m >> 3) & 1) { int ei = emap[e * B_ + 3]; ss3 += base_v + (ei ? Scorr[(ei - 1) * D_ + lane] : 0.f); }
  }
#pragma unroll
  for (int b = 0; b < B_; ++b) {
    if ((m >> b) & 1) {
      float ssb = (b == 0) ? ss0 : (b == 1) ? ss1 : (b == 2) ? ss2 : ss3;
      float hv = 0.f;
#pragma unroll
      for (int j = 0; j < A_; ++j) {
        int sl = b * A_ + j;
        if (seednode[sl] == n) hv += seedvec[sl * D_ + lane];
      }
      float aggv = ssb - hv * rs - ps;
      float out = blv;
#pragma unroll 16
      for (int k = 0; k < 64; ++k) {
        out = fmaf(rlane(aggv, k), WaL[k * 64 + lane], out);
        out = fmaf(rlane(hv, k), WsL[k * 64 + lane], out);
      }
      float mu = wave_sum(out) * (1.f / 64.f);
      float dx = out - mu;
      float var = wave_sum(dx * dx) * (1.f / 64.f);
      float y = dx * rsqrtf(var + 1e-5f) * gv + bev;
      Hcorr[(slot * B_ + b) * D_ + lane] = fmaxf(y, 0.f) + hv;
    }
  }
}

// ---------- K5: layer-2 at candidates only, fused with scoring MLP ----------

__global__ __launch_bounds__(512) void cand_kernel(
    const int* __restrict__ ents, const int* __restrict__ meta,
    const int* __restrict__ deg, const int* __restrict__ bucket,
    const int* __restrict__ edge_list, const int* __restrict__ rel_list,
    const float* __restrict__ pos_table, const float* __restrict__ rel_emb_l,
    const float* __restrict__ H1, const float* __restrict__ Hcorr,
    const int* __restrict__ cmap, const int* __restrict__ dirty_n,
    const float* __restrict__ query_emb,
    const float* __restrict__ Wa, const float* __restrict__ Ws,
    const float* __restrict__ bl_, const float* __restrict__ g_,
    const float* __restrict__ be_,
    const float* __restrict__ W1, const float* __restrict__ b1,
    const float* __restrict__ W2, const float* __restrict__ b2,
    float* __restrict__ out) {
  __shared__ float WaL[64 * 64];
  __shared__ float WsL[64 * 64];
  int t = threadIdx.x;
#pragma unroll
  for (int it = 0; it < 2; ++it) {
    int idx = t + 512 * it;
    reinterpret_cast<float4*>(WaL)[idx] = reinterpret_cast<const float4*>(Wa)[idx];
    reinterpret_cast<float4*>(WsL)[idx] = reinterpret_cast<const float4*>(Ws)[idx];
  }
  __syncthreads();
  int w = blockIdx.x * 8 + (t >> 6);
  int lane = t & 63;
  if (w >= B_ * C_) return;
  int b = w / C_;
  int c = w - b * C_;
  int psn = meta[b];
  int qr = meta[B_ + b];
  int n = ents[(b * C_ + c) * A_ + psn];

  float pv0 = pos_table[1 * D_ + lane], pv1 = pos_table[2 * D_ + lane];
  float pv2 = pos_table[3 * D_ + lane], pv3 = pos_table[4 * D_ + lane];
  float pv4 = pos_table[5 * D_ + lane], pv5 = pos_table[6 * D_ + lane];

  float h1v = H1[n * D_ + lane];
  if ((dirty_n[n] >> b) & 1) h1v = Hcorr[(cmap[n] * B_ + b) * D_ + lane];

  int dg = __builtin_amdgcn_readfirstlane(deg[n]);
  int base = n * DCAP;
  float aggv = 0.f;
  for (int p = 0; p < dg; ++p) {
    int ii = bucket[base + p];
    int e = ii / 6, a = ii - e * 6;
    float rel = rel_emb_l[rel_list[e] * D_ + lane];
    float s = 0.f;
#pragma unroll
    for (int a2 = 0; a2 < A_; ++a2) {
      int m2 = edge_list[e * A_ + a2];
      if (m2) {
        float hm = H1[m2 * D_ + lane];
        if ((dirty_n[m2] >> b) & 1) hm = Hcorr[(cmap[m2] * B_ + b) * D_ + lane];
        float pa2 = sel6(pv0, pv1, pv2, pv3, pv4, pv5, a2);
        s += hm + pa2;
      }
    }
    float pa = sel6(pv0, pv1, pv2, pv3, pv4, pv5, a);
    aggv = fmaf(s - h1v - pa, rel, aggv);
  }

  float outv = bl_[lane];
#pragma unroll 16
  for (int k = 0; k < 64; ++k) {
    outv = fmaf(rlane(aggv, k), WaL[k * 64 + lane], outv);
    outv = fmaf(rlane(h1v, k), WsL[k * 64 + lane], outv);
  }
  float mu = wave_sum(outv) * (1.f / 64.f);
  float dx = outv - mu;
  float var = wave_sum(dx * dx) * (1.f / 64.f);
  float y = dx * rsqrtf(var + 1e-5f) * g_[lane] + be_[lane];
  float h2v = fmaxf(y, 0.f) + h1v;

  float qv = query_emb[qr * D_ + lane];
  float hid0 = b1[lane];
  float hid1 = b1[D_ + lane];
#pragma unroll
  for (int k = 0; k < D_; ++k) {
    float f = rlane(h2v, k);
    hid0 = fmaf(f, W1[k * FEAT_ + lane], hid0);
    hid1 = fmaf(f, W1[k * FEAT_ + D_ + lane], hid1);
  }
#pragma unroll
  for (int k = 0; k < D_; ++k) {
    float q = rlane(qv, k);
    hid0 = fmaf(q, W1[(D_ + k) * FEAT_ + lane], hid0);
    hid1 = fmaf(q, W1[(D_ + k) * FEAT_ + D_ + lane], hid1);
  }
  float accs = fmaxf(hid0, 0.f) * W2[lane] + fmaxf(hid1, 0.f) * W2[D_ + lane];
  accs = wave_sum(accs);
  if (lane == 0) out[w] = accs + b2[0];
}

// ---------- launch ----------

extern "C" void kernel_launch(void* const* d_in, const int* in_sizes, int n_in,
                              void* d_out, int out_size, void* d_ws, size_t ws_size,
                              hipStream_t stream) {
  const int* r_idx = (const int*)d_in[0];
  const int* ents = (const int*)d_in[1];
  const int* arity = (const int*)d_in[2];
  const int* edge_list = (const int*)d_in[3];
  const int* rel_list = (const int*)d_in[4];
  const float* pos_table = (const float*)d_in[5];
  const float* query_emb = (const float*)d_in[6];
  const float* rel_emb = (const float*)d_in[7];
  const float* W_agg = (const float*)d_in[8];
  const float* W_self = (const float*)d_in[9];
  const float* b_lin = (const float*)d_in[10];
  const float* ln_g = (const float*)d_in[11];
  const float* ln_b = (const float*)d_in[12];
  const float* W1 = (const float*)d_in[13];
  const float* b1 = (const float*)d_in[14];
  const float* W2 = (const float*)d_in[15];
  const float* b2 = (const float*)d_in[16];
  float* out = (float*)d_out;

  char* ws = (char*)d_ws;
  // layout (bytes)
  float* H1      = (float*)(ws + 0);           //  5,120,256
  float* Hcorr   = (float*)(ws + 5120512);     // 20,481,024
  float* Scorr   = (float*)(ws + 25601536);    //  2,097,152
  int* cmap      = (int*)(ws + 27698688);      //     80,004
  int* seednode  = (int*)(ws + 27778816);      //         96
  float* seedvec = (float*)(ws + 27778912);    //      6,144
  int* meta      = (int*)(ws + 27785056);      //         32
  int* emask     = (int*)(ws + 27785216);      //    120,000 (non-atomic full write)
  unsigned short* emap = (unsigned short*)(ws + 27905216);  // 240,008 (full write by eps)
  int* bucket    = (int*)(ws + 28145280);      //  5,120,256 (N*DCAP ints)
  // contiguous zero region (cleared by zero_kernel):
  const size_t Z = 33265536;  // 16-aligned
  int* deg       = (int*)(ws + Z);             //     80,016 (padded)
  int* dirtyA    = (int*)(ws + Z + 80016);     //     80,016
  int* dirty_n   = (int*)(ws + Z + 160032);    //     80,016
  int* ctrs      = (int*)(ws + Z + 240048);    //         64
  const size_t ZBYTES = 240112;  // = ZQUADS*16
  if (ws_size < Z + ZBYTES) return;  // insufficient scratch; output stays poisoned

  const float* rel0 = rel_emb;             // layer 0
  const float* rel1 = rel_emb + R_ * D_;   // layer 1

  zero_kernel<<<(ZQUADS + 255) / 256, 256, 0, stream>>>((float4*)(ws + Z));

  init_bucket_kernel<<<IB_BLOCKS, 256, 0, stream>>>(
      r_idx, ents, arity, pos_table, query_emb, edge_list,
      seednode, seedvec, dirtyA, dirty_n, meta, deg, bucket, emask);

  main_eps_kernel<<<MAIN_BLOCKS + EPS_BLOCKS, 256, 0, stream>>>(
      deg, bucket, edge_list, rel_list, emask, pos_table, rel0, H1,
      W_agg, b_lin, ln_g, ln_b,
      dirtyA, dirty_n, seednode, seedvec, Scorr, emap, ctrs);

  corr_kernel<<<(N_ + 3) / 4, 256, 0, stream>>>(
      deg, bucket, rel_list, emask, pos_table, rel0, Scorr, emap,
      dirty_n, seednode, seedvec, cmap, Hcorr,
      W_agg, W_self, b_lin, ln_g, ln_b, ctrs);

  cand_kernel<<<(B_ * C_ + 7) / 8, 512, 0, stream>>>(
      ents, meta, deg, bucket, edge_list, rel_list, pos_table, rel1,
      H1, Hcorr, cmap, dirty_n, query_emb,
      W_agg + D_ * D_, W_self + D_ * D_, b_lin + D_, ln_g + D_, ln_b + D_,
      W1, b1, W2, b2, out);

  (void)in_sizes; (void)n_in; (void)out_size;
}